// Round 2
// baseline (562.144 us; speedup 1.0000x reference)
//
#include <hip/hip_runtime.h>

#define NUM_USER 60000
#define NUM_ITEM 40000
#define NN 100000
#define NE 500000
#define DIM 64
#define KF 4
#define SCAN_CHUNK 512
#define NBLK_SCAN ((NN + 1 + SCAN_CHUNK - 1) / SCAN_CHUNK)
// padded slot-count upper bounds (each node rounds up to multiple of 4)
#define NEPU_MAX (NE + 3 * NUM_USER)   // 680000 user-side slots max
#define NEPI_MAX (NE + 3 * NUM_ITEM)   // 620000 item-side slots max
#define MAXU_SLOTS 40                  // register-cached user path handles <=40 slots

// sum within each 16-lane group (butterfly: all lanes get result)
__device__ __forceinline__ float red16(float v) {
    v += __shfl_xor(v, 1);
    v += __shfl_xor(v, 2);
    v += __shfl_xor(v, 4);
    v += __shfl_xor(v, 8);
    return v;
}

__device__ __forceinline__ float b2f(unsigned short u) {
    return __uint_as_float(((unsigned)u) << 16);
}
__device__ __forceinline__ unsigned short f2b(float x) {
    unsigned u = __float_as_uint(x);
    u = (u + 0x7fffu + ((u >> 16) & 1u)) >> 16;   // RNE
    return (unsigned short)u;
}
// combined item word: high16 = T (bf16 bits), low16 = ego (bf16 bits)
__device__ __forceinline__ float cvt_lo(unsigned c) { return __uint_as_float(c << 16); }
__device__ __forceinline__ float cvt_hi(unsigned c) { return __uint_as_float(c & 0xffff0000u); }
// pack hi16 halves of two combined words: lo16(out)=hi16(c0), hi16(out)=hi16(c1)
__device__ __forceinline__ unsigned packhi(unsigned c0, unsigned c1) {
#if defined(__has_builtin) && __has_builtin(__builtin_amdgcn_perm)
    return __builtin_amdgcn_perm(c1, c0, 0x07060302u);
#else
    return (c0 >> 16) | (c1 & 0xffff0000u);
#endif
}

__device__ __forceinline__ float4 softmax4(float4 s) {
    float m = fmaxf(fmaxf(s.x, s.y), fmaxf(s.z, s.w));
    float e0 = expf(s.x - m), e1 = expf(s.y - m), e2 = expf(s.z - m), e3 = expf(s.w - m);
    float inv = 1.0f / (e0 + e1 + e2 + e3);
    return make_float4(e0 * inv, e1 * inv, e2 * inv, e3 * inv);
}

// wave per node. Users: egoU(bf16) + allemb. Items: cmbI = (tanh(l2n16)<<16)|ego.
__global__ void k_init(const float* __restrict__ user, const float* __restrict__ item,
                       unsigned short* __restrict__ egoU, unsigned* __restrict__ cmbI,
                       float* __restrict__ allemb) {
    int node = (blockIdx.x * blockDim.x + threadIdx.x) >> 6;
    int lane = threadIdx.x & 63;
    if (node >= NN) return;
    int i = node * DIM + lane;
    if (node < NUM_USER) {
        float v = user[i];
        egoU[i] = f2b(v);
        allemb[i] = v;
    } else {
        float v = item[i - NUM_USER * DIM];
        allemb[i] = v;
        float ss = red16(v * v);
        float t = tanhf(v / fmaxf(sqrtf(ss), 1e-12f));
        cmbI[i - NUM_USER * DIM] = (((unsigned)f2b(t)) << 16) | (unsigned)f2b(v);
    }
}

__global__ void k_count(const int* __restrict__ row0, const int* __restrict__ col0,
                        int* __restrict__ cnt) {
    int e = blockIdx.x * blockDim.x + threadIdx.x;
    if (e >= NE) return;
    atomicAdd(&cnt[row0[e]], 1);
    atomicAdd(&cnt[col0[e]], 1);
}

// dinv + padded counts (round degree up to multiple of 4)
__global__ void k_dinv_pad(const int* __restrict__ cnt, float* __restrict__ dinv,
                           int* __restrict__ cntp) {
    int i = blockIdx.x * blockDim.x + threadIdx.x;
    if (i >= NN) return;
    int d = cnt[i];
    dinv[i] = (d > 0) ? rsqrtf((float)d) : 0.0f;
    cntp[i] = (d + 3) & ~3;
}

// --- 3-stage exclusive scan over cntp[NN] -> ptr[NN+1] ---
__global__ void k_scan1(const int* __restrict__ cnt, int* __restrict__ ptr,
                        int* __restrict__ bsum) {
    __shared__ int sm[SCAN_CHUNK];
    int tid = threadIdx.x;
    int idx = blockIdx.x * SCAN_CHUNK + tid;
    int x = (idx < NN) ? cnt[idx] : 0;
    sm[tid] = x;
    __syncthreads();
    for (int off = 1; off < SCAN_CHUNK; off <<= 1) {
        int v = (tid >= off) ? sm[tid - off] : 0;
        __syncthreads();
        sm[tid] += v;
        __syncthreads();
    }
    if (idx <= NN) ptr[idx] = sm[tid] - x;
    if (tid == SCAN_CHUNK - 1) bsum[blockIdx.x] = sm[tid];
}

__global__ void k_scan2(int* __restrict__ bsum, int* __restrict__ offs) {
    __shared__ int sm[256];
    int tid = threadIdx.x;
    int x = (tid < NBLK_SCAN) ? bsum[tid] : 0;
    sm[tid] = x;
    __syncthreads();
    for (int off = 1; off < 256; off <<= 1) {
        int v = (tid >= off) ? sm[tid - off] : 0;
        __syncthreads();
        sm[tid] += v;
        __syncthreads();
    }
    if (tid < NBLK_SCAN) offs[tid] = sm[tid] - x;
}

__global__ void k_scan3(int* __restrict__ ptr, const int* __restrict__ offs) {
    int idx = blockIdx.x * blockDim.x + threadIdx.x;
    if (idx <= NN) ptr[idx] += offs[idx / SCAN_CHUNK];
}

// fill CSR. user-side slots are [0, ptr[NUM_USER]); src stored ITEM-LOCAL there.
// jit[user_slot] = item-local slot of the same edge (for witemT scatter in supd).
__global__ void k_fill(const int* __restrict__ row0, const int* __restrict__ col0,
                       int* __restrict__ pos, const int* __restrict__ ptr,
                       int* __restrict__ srcadj, int* __restrict__ jit,
                       int* __restrict__ jpos1) {
    int e = blockIdx.x * blockDim.x + threadIdx.x;
    if (e >= NE) return;
    int r = row0[e], c = col0[e];
    int ptrU = ptr[NUM_USER];
    int j1 = atomicAdd(&pos[r], 1);   // user-side slot: dst=r, src=c (item-local)
    srcadj[j1] = c - NUM_USER;
    jpos1[e] = j1;
    int j0 = atomicAdd(&pos[c], 1);   // item-side slot: dst=c, src=r
    srcadj[j0] = r;
    jit[j1] = j0 - ptrU;
}

// fill dummy (padding) slots: src=0 (weight is 0 so value harmless)
__global__ void k_pad(const int* __restrict__ cnt, const int* __restrict__ ptr,
                      int* __restrict__ srcadj) {
    int n = blockIdx.x * blockDim.x + threadIdx.x;
    if (n >= NN) return;
    int realend = ptr[n] + cnt[n];
    int end = ptr[n + 1];
    for (int j = realend; j < end; ++j) srcadj[j] = 0;
}

// permute S into slot order, norm per slot, initial weights in BOTH transposed
// layouts (real slots only; dummy slots stay 0 from the memsets)
__global__ void k_w0(const float* __restrict__ Sin, const int* __restrict__ row0,
                     const int* __restrict__ col0, const int* __restrict__ jpos1,
                     const int* __restrict__ jit, const float* __restrict__ dinv,
                     float4* __restrict__ Scur4, float* __restrict__ normu,
                     float* __restrict__ wuserT, float* __restrict__ witemT) {
    int e = blockIdx.x * blockDim.x + threadIdx.x;
    if (e >= NE) return;
    int j = jpos1[e];
    float n = dinv[row0[e]] * dinv[col0[e]];
    float4 s = make_float4(Sin[e], Sin[NE + e], Sin[2 * NE + e], Sin[3 * NE + e]);
    float4 p = softmax4(s);
    Scur4[j] = s;
    normu[j] = n;
    int ji = jit[j];
    wuserT[0 * NEPU_MAX + j] = n * p.x;
    wuserT[1 * NEPU_MAX + j] = n * p.y;
    wuserT[2 * NEPU_MAX + j] = n * p.z;
    wuserT[3 * NEPU_MAX + j] = n * p.w;
    witemT[0 * NEPI_MAX + ji] = n * p.x;
    witemT[1 * NEPI_MAX + ji] = n * p.y;
    witemT[2 * NEPI_MAX + ji] = n * p.z;
    witemT[3 * NEPI_MAX + ji] = n * p.w;
}

// Scur4 (slot order) -> Sout [4][E] original edge order
__global__ void k_sout(const float4* __restrict__ Scur4, const int* __restrict__ jpos1,
                       float* __restrict__ Sout) {
    int e = blockIdx.x * blockDim.x + threadIdx.x;
    if (e >= NE) return;
    float4 s = Scur4[jpos1[e]];
    Sout[e] = s.x;
    Sout[NE + e] = s.y;
    Sout[2 * NE + e] = s.z;
    Sout[3 * NE + e] = s.w;
}

// fused gather conv + routing score. wave per node; lane = dim, k = lane>>4.
// Users: fully-unrolled 5x8-slot guarded blocks (+4-tail); T (hi16 of cmbI word)
// register-cached packed 2/VGPR -> score pass has ZERO memory gathers.
// Items: 8-slot loop, weights as broadcast float4 from transposed witemT.
// flags: 1 = layer end (allemb += acc), 4 = write next ego (items: +tanh T)
__global__ __launch_bounds__(256) void k_conv_score(
        const int* __restrict__ ptr, const int* __restrict__ srcadj,
        const float* __restrict__ wuserT, const float* __restrict__ witemT,
        float* __restrict__ pscore, const unsigned short* __restrict__ egoU,
        const unsigned* __restrict__ cmbI, unsigned short* __restrict__ xnextU,
        unsigned* __restrict__ cmbNext, float* __restrict__ allemb, int flags) {
    int node = (blockIdx.x * blockDim.x + threadIdx.x) >> 6;
    int lane = threadIdx.x & 63;
    if (node >= NN) return;
    int beg = __builtin_amdgcn_readfirstlane(ptr[node]);
    int end = __builtin_amdgcn_readfirstlane(ptr[node + 1]);
    int count = end - beg;
    int k = lane >> 4;

    float a0 = 0.0f, a1 = 0.0f, a2 = 0.0f, a3 = 0.0f;

    if (node >= NUM_USER) {
        // ---- item side: conv only ----
        int ptrU = __builtin_amdgcn_readfirstlane(ptr[NUM_USER]);
        const float* wT = witemT + (size_t)k * NEPI_MAX + (beg - ptrU);
        int t = 0;
        for (; t + 8 <= count; t += 8) {
            int4 sA = *(const int4*)(srcadj + beg + t);
            int4 sB = *(const int4*)(srcadj + beg + t + 4);
            float4 wA = *(const float4*)(wT + t);
            float4 wB = *(const float4*)(wT + t + 4);
            a0 = fmaf(wA.x, b2f(egoU[sA.x * DIM + lane]), a0);
            a1 = fmaf(wA.y, b2f(egoU[sA.y * DIM + lane]), a1);
            a2 = fmaf(wA.z, b2f(egoU[sA.z * DIM + lane]), a2);
            a3 = fmaf(wA.w, b2f(egoU[sA.w * DIM + lane]), a3);
            a0 = fmaf(wB.x, b2f(egoU[sB.x * DIM + lane]), a0);
            a1 = fmaf(wB.y, b2f(egoU[sB.y * DIM + lane]), a1);
            a2 = fmaf(wB.z, b2f(egoU[sB.z * DIM + lane]), a2);
            a3 = fmaf(wB.w, b2f(egoU[sB.w * DIM + lane]), a3);
        }
        if (t < count) {   // 4-slot tail
            int4 sA = *(const int4*)(srcadj + beg + t);
            float4 wA = *(const float4*)(wT + t);
            a0 = fmaf(wA.x, b2f(egoU[sA.x * DIM + lane]), a0);
            a1 = fmaf(wA.y, b2f(egoU[sA.y * DIM + lane]), a1);
            a2 = fmaf(wA.z, b2f(egoU[sA.z * DIM + lane]), a2);
            a3 = fmaf(wA.w, b2f(egoU[sA.w * DIM + lane]), a3);
        }
        float acc = (a0 + a1) + (a2 + a3);
        if (flags & 1) {
            int i = node * DIM + lane;
            allemb[i] += acc;
            if (flags & 4) {
                float ss = red16(acc * acc);
                float tt = tanhf(acc / fmaxf(sqrtf(ss), 1e-12f));
                cmbNext[i - NUM_USER * DIM] =
                    (((unsigned)f2b(tt)) << 16) | (unsigned)f2b(acc);
            }
        }
        return;
    }

    // ---- user side: conv + routing score ----
    const float* wT = wuserT + (size_t)k * NEPU_MAX;
    unsigned tp[20];          // packed T cache: 2 slots per word, static-indexed
    unsigned tpt0 = 0, tpt1 = 0;
    bool big = count > MAXU_SLOTS;   // wave-uniform fallback (statistically never)

    if (!big) {
#pragma unroll
        for (int b = 0; b < 5; ++b) {
            if (count >= 8 * (b + 1)) {
                int j = beg + 8 * b;
                int4 sA = *(const int4*)(srcadj + j);
                int4 sB = *(const int4*)(srcadj + j + 4);
                float4 wA = *(const float4*)(wT + j);
                float4 wB = *(const float4*)(wT + j + 4);
                unsigned c0 = cmbI[sA.x * DIM + lane];
                unsigned c1 = cmbI[sA.y * DIM + lane];
                unsigned c2 = cmbI[sA.z * DIM + lane];
                unsigned c3 = cmbI[sA.w * DIM + lane];
                unsigned c4 = cmbI[sB.x * DIM + lane];
                unsigned c5 = cmbI[sB.y * DIM + lane];
                unsigned c6 = cmbI[sB.z * DIM + lane];
                unsigned c7 = cmbI[sB.w * DIM + lane];
                a0 = fmaf(wA.x, cvt_lo(c0), a0);
                a1 = fmaf(wA.y, cvt_lo(c1), a1);
                a2 = fmaf(wA.z, cvt_lo(c2), a2);
                a3 = fmaf(wA.w, cvt_lo(c3), a3);
                a0 = fmaf(wB.x, cvt_lo(c4), a0);
                a1 = fmaf(wB.y, cvt_lo(c5), a1);
                a2 = fmaf(wB.z, cvt_lo(c6), a2);
                a3 = fmaf(wB.w, cvt_lo(c7), a3);
                tp[4 * b + 0] = packhi(c0, c1);
                tp[4 * b + 1] = packhi(c2, c3);
                tp[4 * b + 2] = packhi(c4, c5);
                tp[4 * b + 3] = packhi(c6, c7);
            }
        }
        if (count & 4) {
            int j = beg + (count & ~7);
            int4 sA = *(const int4*)(srcadj + j);
            float4 wA = *(const float4*)(wT + j);
            unsigned c0 = cmbI[sA.x * DIM + lane];
            unsigned c1 = cmbI[sA.y * DIM + lane];
            unsigned c2 = cmbI[sA.z * DIM + lane];
            unsigned c3 = cmbI[sA.w * DIM + lane];
            a0 = fmaf(wA.x, cvt_lo(c0), a0);
            a1 = fmaf(wA.y, cvt_lo(c1), a1);
            a2 = fmaf(wA.z, cvt_lo(c2), a2);
            a3 = fmaf(wA.w, cvt_lo(c3), a3);
            tpt0 = packhi(c0, c1);
            tpt1 = packhi(c2, c3);
        }
    } else {
        for (int j = beg; j < end; j += 4) {
            int4 s = *(const int4*)(srcadj + j);
            float4 w4 = *(const float4*)(wT + j);
            a0 = fmaf(w4.x, cvt_lo(cmbI[s.x * DIM + lane]), a0);
            a1 = fmaf(w4.y, cvt_lo(cmbI[s.y * DIM + lane]), a1);
            a2 = fmaf(w4.z, cvt_lo(cmbI[s.z * DIM + lane]), a2);
            a3 = fmaf(w4.w, cvt_lo(cmbI[s.w * DIM + lane]), a3);
        }
    }
    float acc = (a0 + a1) + (a2 + a3);

    if (flags & 1) {
        int i = node * DIM + lane;
        allemb[i] += acc;
        if (flags & 4) xnextU[i] = f2b(acc);
    }

    // routing score: pscore[4*jj+k] = <u, T[src_jj]>_16 from REGISTER cache
    float ssu = red16(acc * acc);
    float u = acc / fmaxf(sqrtf(ssu), 1e-12f);
    bool b0 = lane & 1;
    bool b1 = lane & 2;
    bool b2 = lane & 4;

    if (!big) {
#pragma unroll
        for (int b = 0; b < 5; ++b) {
            if (count >= 8 * (b + 1)) {
                int j = beg + 8 * b;
                unsigned t01 = tp[4 * b + 0], t23 = tp[4 * b + 1];
                unsigned t45 = tp[4 * b + 2], t67 = tp[4 * b + 3];
                float p0 = u * __uint_as_float(t01 << 16);
                float p1 = u * __uint_as_float(t01 & 0xffff0000u);
                float p2 = u * __uint_as_float(t23 << 16);
                float p3 = u * __uint_as_float(t23 & 0xffff0000u);
                float p4 = u * __uint_as_float(t45 << 16);
                float p5 = u * __uint_as_float(t45 & 0xffff0000u);
                float p6 = u * __uint_as_float(t67 << 16);
                float p7 = u * __uint_as_float(t67 & 0xffff0000u);
                // 8-value mixed butterfly reduce over 16 lanes:
                // result: lane l holds full dot of slot j+(l&7)
                float q0 = (b0 ? p1 : p0) + __shfl_xor(b0 ? p0 : p1, 1);
                float q1 = (b0 ? p3 : p2) + __shfl_xor(b0 ? p2 : p3, 1);
                float q2 = (b0 ? p5 : p4) + __shfl_xor(b0 ? p4 : p5, 1);
                float q3 = (b0 ? p7 : p6) + __shfl_xor(b0 ? p6 : p7, 1);
                float r0 = (b1 ? q1 : q0) + __shfl_xor(b1 ? q0 : q1, 2);
                float r1 = (b1 ? q3 : q2) + __shfl_xor(b1 ? q2 : q3, 2);
                float t0 = (b2 ? r1 : r0) + __shfl_xor(b2 ? r0 : r1, 4);
                t0 += __shfl_xor(t0, 8);
                if (!(lane & 8)) pscore[4 * (j + (lane & 7)) + k] = t0;
            }
        }
        if (count & 4) {
            int j = beg + (count & ~7);
            float p0 = u * __uint_as_float(tpt0 << 16);
            float p1 = u * __uint_as_float(tpt0 & 0xffff0000u);
            float p2 = u * __uint_as_float(tpt1 << 16);
            float p3 = u * __uint_as_float(tpt1 & 0xffff0000u);
            float q0 = (b0 ? p1 : p0) + __shfl_xor(b0 ? p0 : p1, 1);
            float q1 = (b0 ? p3 : p2) + __shfl_xor(b0 ? p2 : p3, 1);
            float r0 = (b1 ? q1 : q0) + __shfl_xor(b1 ? q0 : q1, 2);
            r0 += __shfl_xor(r0, 4);
            r0 += __shfl_xor(r0, 8);
            if (!(lane & 12)) pscore[4 * (j + (lane & 3)) + k] = r0;
        }
    } else {
        bool lead = (lane & 15) == 0;
        for (int j = beg; j < end; j += 4) {
            int4 s = *(const int4*)(srcadj + j);
            float p0 = red16(u * cvt_hi(cmbI[s.x * DIM + lane]));
            float p1 = red16(u * cvt_hi(cmbI[s.y * DIM + lane]));
            float p2 = red16(u * cvt_hi(cmbI[s.z * DIM + lane]));
            float p3 = red16(u * cvt_hi(cmbI[s.w * DIM + lane]));
            if (lead) {
                pscore[4 * j + k] = p0;
                pscore[4 * j + 4 + k] = p1;
                pscore[4 * j + 8 + k] = p2;
                pscore[4 * j + 12 + k] = p3;
            }
        }
    }
}

// thread per padded user slot: snew = softmax4(S4)+pscore; S4=snew;
// if !last: w = normu * softmax4(snew) -> transposed wuserT (coalesced) +
// scatter to transposed witemT (dummy slots: normu=0 -> w=0, no scatter)
__global__ void k_supd(const int* __restrict__ ptr, float4* __restrict__ S4,
                       const float4* __restrict__ pscore, const float* __restrict__ normu,
                       const int* __restrict__ jit, float* __restrict__ wuserT,
                       float* __restrict__ witemT, int last) {
    int j = blockIdx.x * blockDim.x + threadIdx.x;
    if (j >= ptr[NUM_USER]) return;
    float4 s = softmax4(S4[j]);
    float4 p = pscore[j];
    float4 snew = make_float4(s.x + p.x, s.y + p.y, s.z + p.z, s.w + p.w);
    S4[j] = snew;
    if (!last) {
        float n = normu[j];
        float4 q = softmax4(snew);
        wuserT[0 * NEPU_MAX + j] = n * q.x;
        wuserT[1 * NEPU_MAX + j] = n * q.y;
        wuserT[2 * NEPU_MAX + j] = n * q.z;
        wuserT[3 * NEPU_MAX + j] = n * q.w;
        if (n > 0.0f) {
            int ji = jit[j];
            witemT[0 * NEPI_MAX + ji] = n * q.x;
            witemT[1 * NEPI_MAX + ji] = n * q.y;
            witemT[2 * NEPI_MAX + ji] = n * q.z;
            witemT[3 * NEPI_MAX + ji] = n * q.w;
        }
    }
}

extern "C" void kernel_launch(void* const* d_in, const int* in_sizes, int n_in,
                              void* d_out, int out_size, void* d_ws, size_t ws_size,
                              hipStream_t stream) {
    const float* user = (const float*)d_in[0];
    const float* item = (const float*)d_in[1];
    const float* S_in = (const float*)d_in[2];
    const int* edge = (const int*)d_in[3];
    const int* row0 = edge;
    const int* col0 = edge + NE;

    float* out = (float*)d_out;
    float* allemb = out;              // NN*DIM floats
    float* Sfinal = out + NN * DIM;   // KF*NE floats

    char* ws = (char*)d_ws;
    size_t off = 0;
    auto carve = [&](size_t bytes) { void* p = ws + off; off += (bytes + 255) & ~(size_t)255; return p; };
    int* cnt = (int*)carve((NN + 1) * sizeof(int));
    int* cntp = (int*)carve((NN + 1) * sizeof(int));
    int* ptr = (int*)carve((NN + 1) * sizeof(int));
    int* pos = (int*)carve((NN + 1) * sizeof(int));
    int* bsum = (int*)carve(256 * sizeof(int));
    int* offs = (int*)carve(256 * sizeof(int));
    int* srcadj = (int*)carve((size_t)(NEPU_MAX + NEPI_MAX) * sizeof(int));
    int* jit = (int*)carve((size_t)NEPU_MAX * sizeof(int));
    int* jpos1 = (int*)carve((size_t)NE * sizeof(int));
    float* dinv = (float*)carve(NN * sizeof(float));
    float* normu = (float*)carve((size_t)NEPU_MAX * sizeof(float));
    float4* Scur4 = (float4*)carve((size_t)NEPU_MAX * sizeof(float4));
    float* wuserT = (float*)carve((size_t)4 * NEPU_MAX * sizeof(float));
    float* witemT = (float*)carve((size_t)4 * NEPI_MAX * sizeof(float));
    float4* pscore = (float4*)carve((size_t)NEPU_MAX * sizeof(float4));
    unsigned short* egoUA = (unsigned short*)carve((size_t)NUM_USER * DIM * 2);
    unsigned short* egoUB = (unsigned short*)carve((size_t)NUM_USER * DIM * 2);
    unsigned* cmbIA = (unsigned*)carve((size_t)NUM_ITEM * DIM * 4);
    unsigned* cmbIB = (unsigned*)carve((size_t)NUM_ITEM * DIM * 4);

    hipMemsetAsync(cnt, 0, (NN + 1) * sizeof(int), stream);
    hipMemsetAsync(normu, 0, (size_t)NEPU_MAX * sizeof(float), stream);
    hipMemsetAsync(Scur4, 0, (size_t)NEPU_MAX * sizeof(float4), stream);
    hipMemsetAsync(wuserT, 0, (size_t)4 * NEPU_MAX * sizeof(float), stream);
    hipMemsetAsync(witemT, 0, (size_t)4 * NEPI_MAX * sizeof(float), stream);

    k_count<<<(NE + 255) / 256, 256, 0, stream>>>(row0, col0, cnt);
    k_dinv_pad<<<(NN + 255) / 256, 256, 0, stream>>>(cnt, dinv, cntp);
    k_scan1<<<NBLK_SCAN, SCAN_CHUNK, 0, stream>>>(cntp, ptr, bsum);
    k_scan2<<<1, 256, 0, stream>>>(bsum, offs);
    k_scan3<<<(NN + 1 + 255) / 256, 256, 0, stream>>>(ptr, offs);
    hipMemcpyAsync(pos, ptr, (NN + 1) * sizeof(int), hipMemcpyDeviceToDevice, stream);
    k_fill<<<(NE + 255) / 256, 256, 0, stream>>>(row0, col0, pos, ptr, srcadj, jit, jpos1);
    k_pad<<<(NN + 255) / 256, 256, 0, stream>>>(cnt, ptr, srcadj);
    k_w0<<<(NE + 255) / 256, 256, 0, stream>>>(S_in, row0, col0, jpos1, jit, dinv,
                                               Scur4, normu, wuserT, witemT);
    k_init<<<(NN * 64 + 255) / 256, 256, 0, stream>>>(user, item, egoUA, cmbIA, allemb);

    unsigned short* egoU = egoUA;
    unsigned short* egoUn = egoUB;
    unsigned* cmbI = cmbIA;
    unsigned* cmbIn = cmbIB;
    for (int layer = 0; layer < 2; ++layer) {
        for (int it = 0; it < 2; ++it) {
            int flags = 0;
            if (it == 1) flags |= 1;                   // layer end: allemb += acc
            if (it == 1 && layer == 0) flags |= 4;     // write next ego (+item T)
            k_conv_score<<<(NN * 64 + 255) / 256, 256, 0, stream>>>(
                ptr, srcadj, wuserT, witemT, (float*)pscore, egoU, cmbI,
                egoUn, cmbIn, allemb, flags);
            int last = (layer == 1 && it == 1) ? 1 : 0;
            k_supd<<<(NEPU_MAX + 255) / 256, 256, 0, stream>>>(
                ptr, Scur4, pscore, normu, jit, wuserT, witemT, last);
        }
        unsigned short* t = egoU; egoU = egoUn; egoUn = t;
        unsigned* tc = cmbI; cmbI = cmbIn; cmbIn = tc;
    }
    k_sout<<<(NE + 255) / 256, 256, 0, stream>>>(Scur4, jpos1, Sfinal);
}

// Round 3
// 487.418 us; speedup vs baseline: 1.1533x; 1.1533x over previous
//
#include <hip/hip_runtime.h>

#define NUM_USER 60000
#define NUM_ITEM 40000
#define NN 100000
#define NE 500000
#define DIM 64
#define KF 4
#define SCAN_CHUNK 512
#define NBLK_SCAN ((NN + 1 + SCAN_CHUNK - 1) / SCAN_CHUNK)
// padded slot-count upper bounds (each node rounds up to multiple of 4)
#define NEPU_MAX (NE + 3 * NUM_USER)   // 680000 user-side slots max
#define NEPI_MAX (NE + 3 * NUM_ITEM)   // 620000 item-side slots max
#define MAXU_SLOTS 40                  // register-cached user path handles <=40 slots

// sum within each 16-lane group (butterfly: all lanes get result)
__device__ __forceinline__ float red16(float v) {
    v += __shfl_xor(v, 1);
    v += __shfl_xor(v, 2);
    v += __shfl_xor(v, 4);
    v += __shfl_xor(v, 8);
    return v;
}

__device__ __forceinline__ float b2f(unsigned short u) {
    return __uint_as_float(((unsigned)u) << 16);
}
__device__ __forceinline__ unsigned short f2b(float x) {
    unsigned u = __float_as_uint(x);
    u = (u + 0x7fffu + ((u >> 16) & 1u)) >> 16;   // RNE
    return (unsigned short)u;
}
// combined item word: high16 = T (bf16 bits), low16 = ego (bf16 bits)
__device__ __forceinline__ float cvt_lo(unsigned c) { return __uint_as_float(c << 16); }
__device__ __forceinline__ float cvt_hi(unsigned c) { return __uint_as_float(c & 0xffff0000u); }
// pack hi16 halves of two combined words: lo16(out)=hi16(c0), hi16(out)=hi16(c1)
__device__ __forceinline__ unsigned packhi(unsigned c0, unsigned c1) {
#if defined(__has_builtin) && __has_builtin(__builtin_amdgcn_perm)
    return __builtin_amdgcn_perm(c1, c0, 0x07060302u);
#else
    return (c0 >> 16) | (c1 & 0xffff0000u);
#endif
}

__device__ __forceinline__ float4 softmax4(float4 s) {
    float m = fmaxf(fmaxf(s.x, s.y), fmaxf(s.z, s.w));
    float e0 = expf(s.x - m), e1 = expf(s.y - m), e2 = expf(s.z - m), e3 = expf(s.w - m);
    float inv = 1.0f / (e0 + e1 + e2 + e3);
    return make_float4(e0 * inv, e1 * inv, e2 * inv, e3 * inv);
}

// Fused per-slot S/weight update. Lane layout: lane holds dot for
// (slot jj, factor k); factor partners are lanes 16 apart. All 64 lanes
// participate in shuffles; stores predicated by 'wr'.
// snew = softmax_k(S4[jj]) + dot; S4 <- snew;
// if !last: w = normu[jj] * softmax_k(snew) -> wuN[4*jj+k], wiN[4*jit[jj]+k]
__device__ __forceinline__ void fused_upd(int jj, int k, float dot, bool wr,
        float* __restrict__ S4f, const float* __restrict__ normu,
        const int* __restrict__ jit, float* __restrict__ wuN,
        float* __restrict__ wiN, int last) {
    float sold = S4f[4 * jj + k];
    float m = fmaxf(sold, __shfl_xor(sold, 16));
    m = fmaxf(m, __shfl_xor(m, 32));
    float e = expf(sold - m);
    float sum = e + __shfl_xor(e, 16);
    sum += __shfl_xor(sum, 32);
    float snew = e * (1.0f / sum) + dot;
    if (wr) S4f[4 * jj + k] = snew;
    if (!last) {
        float m2 = fmaxf(snew, __shfl_xor(snew, 16));
        m2 = fmaxf(m2, __shfl_xor(m2, 32));
        float e2 = expf(snew - m2);
        float s2 = e2 + __shfl_xor(e2, 16);
        s2 += __shfl_xor(s2, 32);
        float n = normu[jj];
        if (wr && n > 0.0f) {
            float w = n * e2 * (1.0f / s2);
            wuN[4 * jj + k] = w;
            wiN[4 * jit[jj] + k] = w;
        }
    }
}

// wave per node. Users: egoU(bf16) + allemb. Items: cmbI = (tanh(l2n16)<<16)|ego.
__global__ void k_init(const float* __restrict__ user, const float* __restrict__ item,
                       unsigned short* __restrict__ egoU, unsigned* __restrict__ cmbI,
                       float* __restrict__ allemb) {
    int node = (blockIdx.x * blockDim.x + threadIdx.x) >> 6;
    int lane = threadIdx.x & 63;
    if (node >= NN) return;
    int i = node * DIM + lane;
    if (node < NUM_USER) {
        float v = user[i];
        egoU[i] = f2b(v);
        allemb[i] = v;
    } else {
        float v = item[i - NUM_USER * DIM];
        allemb[i] = v;
        float ss = red16(v * v);
        float t = tanhf(v / fmaxf(sqrtf(ss), 1e-12f));
        cmbI[i - NUM_USER * DIM] = (((unsigned)f2b(t)) << 16) | (unsigned)f2b(v);
    }
}

__global__ void k_count(const int* __restrict__ row0, const int* __restrict__ col0,
                        int* __restrict__ cnt) {
    int e = blockIdx.x * blockDim.x + threadIdx.x;
    if (e >= NE) return;
    atomicAdd(&cnt[row0[e]], 1);
    atomicAdd(&cnt[col0[e]], 1);
}

// dinv + padded counts (round degree up to multiple of 4)
__global__ void k_dinv_pad(const int* __restrict__ cnt, float* __restrict__ dinv,
                           int* __restrict__ cntp) {
    int i = blockIdx.x * blockDim.x + threadIdx.x;
    if (i >= NN) return;
    int d = cnt[i];
    dinv[i] = (d > 0) ? rsqrtf((float)d) : 0.0f;
    cntp[i] = (d + 3) & ~3;
}

// --- 3-stage exclusive scan over cntp[NN] -> ptr[NN+1] ---
__global__ void k_scan1(const int* __restrict__ cnt, int* __restrict__ ptr,
                        int* __restrict__ bsum) {
    __shared__ int sm[SCAN_CHUNK];
    int tid = threadIdx.x;
    int idx = blockIdx.x * SCAN_CHUNK + tid;
    int x = (idx < NN) ? cnt[idx] : 0;
    sm[tid] = x;
    __syncthreads();
    for (int off = 1; off < SCAN_CHUNK; off <<= 1) {
        int v = (tid >= off) ? sm[tid - off] : 0;
        __syncthreads();
        sm[tid] += v;
        __syncthreads();
    }
    if (idx <= NN) ptr[idx] = sm[tid] - x;
    if (tid == SCAN_CHUNK - 1) bsum[blockIdx.x] = sm[tid];
}

__global__ void k_scan2(int* __restrict__ bsum, int* __restrict__ offs) {
    __shared__ int sm[256];
    int tid = threadIdx.x;
    int x = (tid < NBLK_SCAN) ? bsum[tid] : 0;
    sm[tid] = x;
    __syncthreads();
    for (int off = 1; off < 256; off <<= 1) {
        int v = (tid >= off) ? sm[tid - off] : 0;
        __syncthreads();
        sm[tid] += v;
        __syncthreads();
    }
    if (tid < NBLK_SCAN) offs[tid] = sm[tid] - x;
}

__global__ void k_scan3(int* __restrict__ ptr, const int* __restrict__ offs) {
    int idx = blockIdx.x * blockDim.x + threadIdx.x;
    if (idx <= NN) ptr[idx] += offs[idx / SCAN_CHUNK];
}

// fill CSR. user-side slots are [0, ptr[NUM_USER]); src stored ITEM-LOCAL there.
// jit[user_slot] = item-local slot of the same edge (for witem scatter).
__global__ void k_fill(const int* __restrict__ row0, const int* __restrict__ col0,
                       int* __restrict__ pos, const int* __restrict__ ptr,
                       int* __restrict__ srcadj, int* __restrict__ jit,
                       int* __restrict__ jpos1) {
    int e = blockIdx.x * blockDim.x + threadIdx.x;
    if (e >= NE) return;
    int r = row0[e], c = col0[e];
    int ptrU = ptr[NUM_USER];
    int j1 = atomicAdd(&pos[r], 1);   // user-side slot: dst=r, src=c (item-local)
    srcadj[j1] = c - NUM_USER;
    jpos1[e] = j1;
    int j0 = atomicAdd(&pos[c], 1);   // item-side slot: dst=c, src=r
    srcadj[j0] = r;
    jit[j1] = j0 - ptrU;
}

// fill dummy (padding) slots: src=0 (weight is 0 so value harmless)
__global__ void k_pad(const int* __restrict__ cnt, const int* __restrict__ ptr,
                      int* __restrict__ srcadj) {
    int n = blockIdx.x * blockDim.x + threadIdx.x;
    if (n >= NN) return;
    int realend = ptr[n] + cnt[n];
    int end = ptr[n + 1];
    for (int j = realend; j < end; ++j) srcadj[j] = 0;
}

// permute S into slot order, norm per slot, initial weights (interleaved float4,
// both orderings; real slots only; dummy slots stay 0 from the memsets)
__global__ void k_w0(const float* __restrict__ Sin, const int* __restrict__ row0,
                     const int* __restrict__ col0, const int* __restrict__ jpos1,
                     const int* __restrict__ jit, const float* __restrict__ dinv,
                     float4* __restrict__ Scur4, float* __restrict__ normu,
                     float4* __restrict__ wuA, float4* __restrict__ wiA) {
    int e = blockIdx.x * blockDim.x + threadIdx.x;
    if (e >= NE) return;
    int j = jpos1[e];
    float n = dinv[row0[e]] * dinv[col0[e]];
    float4 s = make_float4(Sin[e], Sin[NE + e], Sin[2 * NE + e], Sin[3 * NE + e]);
    float4 p = softmax4(s);
    Scur4[j] = s;
    normu[j] = n;
    float4 w = make_float4(n * p.x, n * p.y, n * p.z, n * p.w);
    wuA[j] = w;
    wiA[jit[j]] = w;
}

// Scur4 (slot order) -> Sout [4][E] original edge order
__global__ void k_sout(const float4* __restrict__ Scur4, const int* __restrict__ jpos1,
                       float* __restrict__ Sout) {
    int e = blockIdx.x * blockDim.x + threadIdx.x;
    if (e >= NE) return;
    float4 s = Scur4[jpos1[e]];
    Sout[e] = s.x;
    Sout[NE + e] = s.y;
    Sout[2 * NE + e] = s.z;
    Sout[3 * NE + e] = s.w;
}

// fused gather conv + routing score + S/weight update (supd folded in).
// wave per node; lane = dim, k = lane>>4 = factor.
// Users: unrolled 5x8-slot guarded blocks (+4-tail); T (hi16 of cmbI) register-
// cached packed 2/VGPR -> score pass has zero memory gathers; per-block fused
// S4/weight update writes NEXT weight buffers (double-buffered vs item readers).
// Items: 8-slot loop, weights dword-broadcast from interleaved wiCur.
// flags: 1 = layer end (allemb += acc), 4 = write next ego (items: +tanh T)
__global__ __launch_bounds__(256) void k_conv_score(
        const int* __restrict__ ptr, const int* __restrict__ srcadj,
        const float* __restrict__ wuCur, const float* __restrict__ wiCur,
        float* __restrict__ S4f, const float* __restrict__ normu,
        const int* __restrict__ jit, float* __restrict__ wuN,
        float* __restrict__ wiN, const unsigned short* __restrict__ egoU,
        const unsigned* __restrict__ cmbI, unsigned short* __restrict__ xnextU,
        unsigned* __restrict__ cmbNext, float* __restrict__ allemb,
        int flags, int last) {
    int node = (blockIdx.x * blockDim.x + threadIdx.x) >> 6;
    int lane = threadIdx.x & 63;
    if (node >= NN) return;
    int beg = __builtin_amdgcn_readfirstlane(ptr[node]);
    int end = __builtin_amdgcn_readfirstlane(ptr[node + 1]);
    int count = end - beg;
    int k = lane >> 4;

    float a0 = 0.0f, a1 = 0.0f, a2 = 0.0f, a3 = 0.0f;

    if (node >= NUM_USER) {
        // ---- item side: conv only ----
        int ptrU = __builtin_amdgcn_readfirstlane(ptr[NUM_USER]);
        const float* wT = wiCur + (size_t)4 * (beg - ptrU);
        int t = 0;
        for (; t + 8 <= count; t += 8) {
            int4 sA = *(const int4*)(srcadj + beg + t);
            int4 sB = *(const int4*)(srcadj + beg + t + 4);
            float w0 = wT[4 * t + k], w1 = wT[4 * t + 4 + k];
            float w2 = wT[4 * t + 8 + k], w3 = wT[4 * t + 12 + k];
            float w4 = wT[4 * t + 16 + k], w5 = wT[4 * t + 20 + k];
            float w6 = wT[4 * t + 24 + k], w7 = wT[4 * t + 28 + k];
            a0 = fmaf(w0, b2f(egoU[sA.x * DIM + lane]), a0);
            a1 = fmaf(w1, b2f(egoU[sA.y * DIM + lane]), a1);
            a2 = fmaf(w2, b2f(egoU[sA.z * DIM + lane]), a2);
            a3 = fmaf(w3, b2f(egoU[sA.w * DIM + lane]), a3);
            a0 = fmaf(w4, b2f(egoU[sB.x * DIM + lane]), a0);
            a1 = fmaf(w5, b2f(egoU[sB.y * DIM + lane]), a1);
            a2 = fmaf(w6, b2f(egoU[sB.z * DIM + lane]), a2);
            a3 = fmaf(w7, b2f(egoU[sB.w * DIM + lane]), a3);
        }
        if (t < count) {   // 4-slot tail
            int4 sA = *(const int4*)(srcadj + beg + t);
            float w0 = wT[4 * t + k], w1 = wT[4 * t + 4 + k];
            float w2 = wT[4 * t + 8 + k], w3 = wT[4 * t + 12 + k];
            a0 = fmaf(w0, b2f(egoU[sA.x * DIM + lane]), a0);
            a1 = fmaf(w1, b2f(egoU[sA.y * DIM + lane]), a1);
            a2 = fmaf(w2, b2f(egoU[sA.z * DIM + lane]), a2);
            a3 = fmaf(w3, b2f(egoU[sA.w * DIM + lane]), a3);
        }
        float acc = (a0 + a1) + (a2 + a3);
        if (flags & 1) {
            int i = node * DIM + lane;
            allemb[i] += acc;
            if (flags & 4) {
                float ss = red16(acc * acc);
                float tt = tanhf(acc / fmaxf(sqrtf(ss), 1e-12f));
                cmbNext[i - NUM_USER * DIM] =
                    (((unsigned)f2b(tt)) << 16) | (unsigned)f2b(acc);
            }
        }
        return;
    }

    // ---- user side: conv + routing score + fused S/w update ----
    unsigned tp[20];          // packed T cache: 2 slots per word, static-indexed
    unsigned tpt0 = 0, tpt1 = 0;
    bool big = count > MAXU_SLOTS;   // wave-uniform fallback (statistically never)

    if (!big) {
#pragma unroll
        for (int b = 0; b < 5; ++b) {
            if (count >= 8 * (b + 1)) {
                int j = beg + 8 * b;
                int4 sA = *(const int4*)(srcadj + j);
                int4 sB = *(const int4*)(srcadj + j + 4);
                float w0 = wuCur[4 * j + k], w1 = wuCur[4 * j + 4 + k];
                float w2 = wuCur[4 * j + 8 + k], w3 = wuCur[4 * j + 12 + k];
                float w4 = wuCur[4 * j + 16 + k], w5 = wuCur[4 * j + 20 + k];
                float w6 = wuCur[4 * j + 24 + k], w7 = wuCur[4 * j + 28 + k];
                unsigned c0 = cmbI[sA.x * DIM + lane];
                unsigned c1 = cmbI[sA.y * DIM + lane];
                unsigned c2 = cmbI[sA.z * DIM + lane];
                unsigned c3 = cmbI[sA.w * DIM + lane];
                unsigned c4 = cmbI[sB.x * DIM + lane];
                unsigned c5 = cmbI[sB.y * DIM + lane];
                unsigned c6 = cmbI[sB.z * DIM + lane];
                unsigned c7 = cmbI[sB.w * DIM + lane];
                a0 = fmaf(w0, cvt_lo(c0), a0);
                a1 = fmaf(w1, cvt_lo(c1), a1);
                a2 = fmaf(w2, cvt_lo(c2), a2);
                a3 = fmaf(w3, cvt_lo(c3), a3);
                a0 = fmaf(w4, cvt_lo(c4), a0);
                a1 = fmaf(w5, cvt_lo(c5), a1);
                a2 = fmaf(w6, cvt_lo(c6), a2);
                a3 = fmaf(w7, cvt_lo(c7), a3);
                tp[4 * b + 0] = packhi(c0, c1);
                tp[4 * b + 1] = packhi(c2, c3);
                tp[4 * b + 2] = packhi(c4, c5);
                tp[4 * b + 3] = packhi(c6, c7);
            }
        }
        if (count & 4) {
            int j = beg + (count & ~7);
            int4 sA = *(const int4*)(srcadj + j);
            float w0 = wuCur[4 * j + k], w1 = wuCur[4 * j + 4 + k];
            float w2 = wuCur[4 * j + 8 + k], w3 = wuCur[4 * j + 12 + k];
            unsigned c0 = cmbI[sA.x * DIM + lane];
            unsigned c1 = cmbI[sA.y * DIM + lane];
            unsigned c2 = cmbI[sA.z * DIM + lane];
            unsigned c3 = cmbI[sA.w * DIM + lane];
            a0 = fmaf(w0, cvt_lo(c0), a0);
            a1 = fmaf(w1, cvt_lo(c1), a1);
            a2 = fmaf(w2, cvt_lo(c2), a2);
            a3 = fmaf(w3, cvt_lo(c3), a3);
            tpt0 = packhi(c0, c1);
            tpt1 = packhi(c2, c3);
        }
    } else {
        for (int j = beg; j < end; j += 4) {
            int4 s = *(const int4*)(srcadj + j);
            float w0 = wuCur[4 * j + k], w1 = wuCur[4 * j + 4 + k];
            float w2 = wuCur[4 * j + 8 + k], w3 = wuCur[4 * j + 12 + k];
            a0 = fmaf(w0, cvt_lo(cmbI[s.x * DIM + lane]), a0);
            a1 = fmaf(w1, cvt_lo(cmbI[s.y * DIM + lane]), a1);
            a2 = fmaf(w2, cvt_lo(cmbI[s.z * DIM + lane]), a2);
            a3 = fmaf(w3, cvt_lo(cmbI[s.w * DIM + lane]), a3);
        }
    }
    float acc = (a0 + a1) + (a2 + a3);

    if (flags & 1) {
        int i = node * DIM + lane;
        allemb[i] += acc;
        if (flags & 4) xnextU[i] = f2b(acc);
    }

    // routing score from REGISTER cache + fused per-slot S/weight update
    float ssu = red16(acc * acc);
    float u = acc / fmaxf(sqrtf(ssu), 1e-12f);
    bool b0 = lane & 1;
    bool b1 = lane & 2;
    bool b2 = lane & 4;

    if (!big) {
#pragma unroll
        for (int b = 0; b < 5; ++b) {
            if (count >= 8 * (b + 1)) {
                int j = beg + 8 * b;
                unsigned t01 = tp[4 * b + 0], t23 = tp[4 * b + 1];
                unsigned t45 = tp[4 * b + 2], t67 = tp[4 * b + 3];
                float p0 = u * __uint_as_float(t01 << 16);
                float p1 = u * __uint_as_float(t01 & 0xffff0000u);
                float p2 = u * __uint_as_float(t23 << 16);
                float p3 = u * __uint_as_float(t23 & 0xffff0000u);
                float p4 = u * __uint_as_float(t45 << 16);
                float p5 = u * __uint_as_float(t45 & 0xffff0000u);
                float p6 = u * __uint_as_float(t67 << 16);
                float p7 = u * __uint_as_float(t67 & 0xffff0000u);
                // 8-value mixed butterfly reduce over 16 lanes:
                // after folding bits 3, lane l holds full dot of slot j+(l&7)
                float q0 = (b0 ? p1 : p0) + __shfl_xor(b0 ? p0 : p1, 1);
                float q1 = (b0 ? p3 : p2) + __shfl_xor(b0 ? p2 : p3, 1);
                float q2 = (b0 ? p5 : p4) + __shfl_xor(b0 ? p4 : p5, 1);
                float q3 = (b0 ? p7 : p6) + __shfl_xor(b0 ? p6 : p7, 1);
                float r0 = (b1 ? q1 : q0) + __shfl_xor(b1 ? q0 : q1, 2);
                float r1 = (b1 ? q3 : q2) + __shfl_xor(b1 ? q2 : q3, 2);
                float t0 = (b2 ? r1 : r0) + __shfl_xor(b2 ? r0 : r1, 4);
                t0 += __shfl_xor(t0, 8);
                fused_upd(j + (lane & 7), k, t0, !(lane & 8),
                          S4f, normu, jit, wuN, wiN, last);
            }
        }
        if (count & 4) {
            int j = beg + (count & ~7);
            float p0 = u * __uint_as_float(tpt0 << 16);
            float p1 = u * __uint_as_float(tpt0 & 0xffff0000u);
            float p2 = u * __uint_as_float(tpt1 << 16);
            float p3 = u * __uint_as_float(tpt1 & 0xffff0000u);
            float q0 = (b0 ? p1 : p0) + __shfl_xor(b0 ? p0 : p1, 1);
            float q1 = (b0 ? p3 : p2) + __shfl_xor(b0 ? p2 : p3, 1);
            float r0 = (b1 ? q1 : q0) + __shfl_xor(b1 ? q0 : q1, 2);
            r0 += __shfl_xor(r0, 4);
            r0 += __shfl_xor(r0, 8);
            fused_upd(j + (lane & 3), k, r0, !(lane & 12),
                      S4f, normu, jit, wuN, wiN, last);
        }
    } else {
        for (int j = beg; j < end; j += 4) {
            int4 s = *(const int4*)(srcadj + j);
            float p0 = red16(u * cvt_hi(cmbI[s.x * DIM + lane]));
            float p1 = red16(u * cvt_hi(cmbI[s.y * DIM + lane]));
            float p2 = red16(u * cvt_hi(cmbI[s.z * DIM + lane]));
            float p3 = red16(u * cvt_hi(cmbI[s.w * DIM + lane]));
            int sl = lane & 3;
            float dv = p0;
            dv = (sl == 1) ? p1 : dv;
            dv = (sl == 2) ? p2 : dv;
            dv = (sl == 3) ? p3 : dv;
            fused_upd(j + sl, k, dv, !(lane & 12),
                      S4f, normu, jit, wuN, wiN, last);
        }
    }
}

extern "C" void kernel_launch(void* const* d_in, const int* in_sizes, int n_in,
                              void* d_out, int out_size, void* d_ws, size_t ws_size,
                              hipStream_t stream) {
    const float* user = (const float*)d_in[0];
    const float* item = (const float*)d_in[1];
    const float* S_in = (const float*)d_in[2];
    const int* edge = (const int*)d_in[3];
    const int* row0 = edge;
    const int* col0 = edge + NE;

    float* out = (float*)d_out;
    float* allemb = out;              // NN*DIM floats
    float* Sfinal = out + NN * DIM;   // KF*NE floats

    char* ws = (char*)d_ws;
    size_t off = 0;
    auto carve = [&](size_t bytes) { void* p = ws + off; off += (bytes + 255) & ~(size_t)255; return p; };
    int* cnt = (int*)carve((NN + 1) * sizeof(int));
    int* cntp = (int*)carve((NN + 1) * sizeof(int));
    int* ptr = (int*)carve((NN + 1) * sizeof(int));
    int* pos = (int*)carve((NN + 1) * sizeof(int));
    int* bsum = (int*)carve(256 * sizeof(int));
    int* offs = (int*)carve(256 * sizeof(int));
    int* srcadj = (int*)carve((size_t)(NEPU_MAX + NEPI_MAX) * sizeof(int));
    int* jit = (int*)carve((size_t)NEPU_MAX * sizeof(int));
    int* jpos1 = (int*)carve((size_t)NE * sizeof(int));
    float* dinv = (float*)carve(NN * sizeof(float));
    float* normu = (float*)carve((size_t)NEPU_MAX * sizeof(float));
    float4* Scur4 = (float4*)carve((size_t)NEPU_MAX * sizeof(float4));
    float4* wuA = (float4*)carve((size_t)NEPU_MAX * sizeof(float4));
    float4* wuB = (float4*)carve((size_t)NEPU_MAX * sizeof(float4));
    float4* wiA = (float4*)carve((size_t)NEPI_MAX * sizeof(float4));
    float4* wiB = (float4*)carve((size_t)NEPI_MAX * sizeof(float4));
    unsigned short* egoUA = (unsigned short*)carve((size_t)NUM_USER * DIM * 2);
    unsigned short* egoUB = (unsigned short*)carve((size_t)NUM_USER * DIM * 2);
    unsigned* cmbIA = (unsigned*)carve((size_t)NUM_ITEM * DIM * 4);
    unsigned* cmbIB = (unsigned*)carve((size_t)NUM_ITEM * DIM * 4);

    hipMemsetAsync(cnt, 0, (NN + 1) * sizeof(int), stream);
    hipMemsetAsync(normu, 0, (size_t)NEPU_MAX * sizeof(float), stream);
    hipMemsetAsync(Scur4, 0, (size_t)NEPU_MAX * sizeof(float4), stream);
    hipMemsetAsync(wuA, 0, (size_t)NEPU_MAX * sizeof(float4), stream);
    hipMemsetAsync(wuB, 0, (size_t)NEPU_MAX * sizeof(float4), stream);
    hipMemsetAsync(wiA, 0, (size_t)NEPI_MAX * sizeof(float4), stream);
    hipMemsetAsync(wiB, 0, (size_t)NEPI_MAX * sizeof(float4), stream);

    k_count<<<(NE + 255) / 256, 256, 0, stream>>>(row0, col0, cnt);
    k_dinv_pad<<<(NN + 255) / 256, 256, 0, stream>>>(cnt, dinv, cntp);
    k_scan1<<<NBLK_SCAN, SCAN_CHUNK, 0, stream>>>(cntp, ptr, bsum);
    k_scan2<<<1, 256, 0, stream>>>(bsum, offs);
    k_scan3<<<(NN + 1 + 255) / 256, 256, 0, stream>>>(ptr, offs);
    hipMemcpyAsync(pos, ptr, (NN + 1) * sizeof(int), hipMemcpyDeviceToDevice, stream);
    k_fill<<<(NE + 255) / 256, 256, 0, stream>>>(row0, col0, pos, ptr, srcadj, jit, jpos1);
    k_pad<<<(NN + 255) / 256, 256, 0, stream>>>(cnt, ptr, srcadj);
    k_w0<<<(NE + 255) / 256, 256, 0, stream>>>(S_in, row0, col0, jpos1, jit, dinv,
                                               Scur4, normu, wuA, wiA);
    k_init<<<(NN * 64 + 255) / 256, 256, 0, stream>>>(user, item, egoUA, cmbIA, allemb);

    unsigned short* egoU = egoUA;
    unsigned short* egoUn = egoUB;
    unsigned* cmbI = cmbIA;
    unsigned* cmbIn = cmbIB;
    float* wuCur = (float*)wuA;
    float* wuNxt = (float*)wuB;
    float* wiCur = (float*)wiA;
    float* wiNxt = (float*)wiB;
    for (int layer = 0; layer < 2; ++layer) {
        for (int it = 0; it < 2; ++it) {
            int flags = 0;
            if (it == 1) flags |= 1;                   // layer end: allemb += acc
            if (it == 1 && layer == 0) flags |= 4;     // write next ego (+item T)
            int last = (layer == 1 && it == 1) ? 1 : 0;
            k_conv_score<<<(NN * 64 + 255) / 256, 256, 0, stream>>>(
                ptr, srcadj, wuCur, wiCur, (float*)Scur4, normu, jit,
                wuNxt, wiNxt, egoU, cmbI, egoUn, cmbIn, allemb, flags, last);
            float* t = wuCur; wuCur = wuNxt; wuNxt = t;
            t = wiCur; wiCur = wiNxt; wiNxt = t;
        }
        unsigned short* t = egoU; egoU = egoUn; egoUn = t;
        unsigned* tc = cmbI; cmbI = cmbIn; cmbIn = tc;
    }
    k_sout<<<(NE + 255) / 256, 256, 0, stream>>>(Scur4, jpos1, Sfinal);
}

// Round 4
// 450.516 us; speedup vs baseline: 1.2478x; 1.0819x over previous
//
#include <hip/hip_runtime.h>

#define NUM_USER 60000
#define NUM_ITEM 40000
#define NN 100000
#define NE 500000
#define DIM 64
#define KF 4
#define SCAN_CHUNK 512
#define NBLK_SCAN ((NN + 1 + SCAN_CHUNK - 1) / SCAN_CHUNK)
// padded slot-count upper bounds (each node rounds up to multiple of 4)
#define NEPU_MAX (NE + 3 * NUM_USER)   // 680000 user-side slots max
#define NEPI_MAX (NE + 3 * NUM_ITEM)   // 620000 item-side slots max
#define MAXU_SLOTS 44                  // register-cached user path handles <=44 slots

// sum within each 16-lane group (butterfly: all lanes get result)
__device__ __forceinline__ float red16(float v) {
    v += __shfl_xor(v, 1);
    v += __shfl_xor(v, 2);
    v += __shfl_xor(v, 4);
    v += __shfl_xor(v, 8);
    return v;
}

__device__ __forceinline__ float b2f(unsigned short u) {
    return __uint_as_float(((unsigned)u) << 16);
}
__device__ __forceinline__ unsigned short f2b(float x) {
    unsigned u = __float_as_uint(x);
    u = (u + 0x7fffu + ((u >> 16) & 1u)) >> 16;   // RNE
    return (unsigned short)u;
}
// combined item word: high16 = T (bf16 bits), low16 = ego (bf16 bits)
__device__ __forceinline__ float cvt_lo(unsigned c) { return __uint_as_float(c << 16); }
__device__ __forceinline__ float cvt_hi(unsigned c) { return __uint_as_float(c & 0xffff0000u); }
// pack hi16 halves of two combined words: lo16(out)=hi16(c0), hi16(out)=hi16(c1)
__device__ __forceinline__ unsigned packhi(unsigned c0, unsigned c1) {
#if defined(__has_builtin) && __has_builtin(__builtin_amdgcn_perm)
    return __builtin_amdgcn_perm(c1, c0, 0x07060302u);
#else
    return (c0 >> 16) | (c1 & 0xffff0000u);
#endif
}
// mixed-butterfly level: lane keeps the value whose slot-bit matches its lane bit
__device__ __forceinline__ float mixv(float x, float y, bool b, int m) {
    return (b ? y : x) + __shfl_xor(b ? x : y, m);
}

__device__ __forceinline__ float4 softmax4(float4 s) {
    float m = fmaxf(fmaxf(s.x, s.y), fmaxf(s.z, s.w));
    float e0 = expf(s.x - m), e1 = expf(s.y - m), e2 = expf(s.z - m), e3 = expf(s.w - m);
    float inv = 1.0f / (e0 + e1 + e2 + e3);
    return make_float4(e0 * inv, e1 * inv, e2 * inv, e3 * inv);
}

// Fused per-slot S/weight update. Lane holds dot for (slot jj, factor k);
// factor partners are lanes 16 apart. softmax(S_old) is reconstructed as
// w_cur * (1/n)  (w_cur is L1-hot from the conv loop) -- no S state traffic.
// snew = w*rn + dot; last: S4f <- snew (final output);
// else: w' = n * softmax_k(snew) -> wuN, wiN (dummy slots n=0: skipped).
__device__ __forceinline__ void fused_upd(int jj, int k, float dot, bool wr,
        const float* __restrict__ wuCur, float* __restrict__ S4f,
        const float2* __restrict__ norm2, const int* __restrict__ jit,
        float* __restrict__ wuN, float* __restrict__ wiN, int last) {
    float w = wuCur[4 * jj + k];
    float2 nn = norm2[jj];
    float snew = fmaf(w, nn.y, dot);
    if (last) {
        if (wr) S4f[4 * jj + k] = snew;
        return;
    }
    float m2 = fmaxf(snew, __shfl_xor(snew, 16));
    m2 = fmaxf(m2, __shfl_xor(m2, 32));
    float e2 = expf(snew - m2);
    float s2 = e2 + __shfl_xor(e2, 16);
    s2 += __shfl_xor(s2, 32);
    if (wr && nn.x > 0.0f) {
        float wn = nn.x * e2 * (1.0f / s2);
        wuN[4 * jj + k] = wn;
        wiN[4 * jit[jj] + k] = wn;
    }
}

// wave per node. Users: egoU(bf16) + allemb. Items: cmbI = (tanh(l2n16)<<16)|ego.
__global__ void k_init(const float* __restrict__ user, const float* __restrict__ item,
                       unsigned short* __restrict__ egoU, unsigned* __restrict__ cmbI,
                       float* __restrict__ allemb) {
    int node = (blockIdx.x * blockDim.x + threadIdx.x) >> 6;
    int lane = threadIdx.x & 63;
    if (node >= NN) return;
    int i = node * DIM + lane;
    if (node < NUM_USER) {
        float v = user[i];
        egoU[i] = f2b(v);
        allemb[i] = v;
    } else {
        float v = item[i - NUM_USER * DIM];
        allemb[i] = v;
        float ss = red16(v * v);
        float t = tanhf(v / fmaxf(sqrtf(ss), 1e-12f));
        cmbI[i - NUM_USER * DIM] = (((unsigned)f2b(t)) << 16) | (unsigned)f2b(v);
    }
}

__global__ void k_count(const int* __restrict__ row0, const int* __restrict__ col0,
                        int* __restrict__ cnt) {
    int e = blockIdx.x * blockDim.x + threadIdx.x;
    if (e >= NE) return;
    atomicAdd(&cnt[row0[e]], 1);
    atomicAdd(&cnt[col0[e]], 1);
}

// dinv + padded counts (round degree up to multiple of 4)
__global__ void k_dinv_pad(const int* __restrict__ cnt, float* __restrict__ dinv,
                           int* __restrict__ cntp) {
    int i = blockIdx.x * blockDim.x + threadIdx.x;
    if (i >= NN) return;
    int d = cnt[i];
    dinv[i] = (d > 0) ? rsqrtf((float)d) : 0.0f;
    cntp[i] = (d + 3) & ~3;
}

// --- 3-stage exclusive scan over cntp[NN] -> ptr[NN+1] ---
__global__ void k_scan1(const int* __restrict__ cnt, int* __restrict__ ptr,
                        int* __restrict__ bsum) {
    __shared__ int sm[SCAN_CHUNK];
    int tid = threadIdx.x;
    int idx = blockIdx.x * SCAN_CHUNK + tid;
    int x = (idx < NN) ? cnt[idx] : 0;
    sm[tid] = x;
    __syncthreads();
    for (int off = 1; off < SCAN_CHUNK; off <<= 1) {
        int v = (tid >= off) ? sm[tid - off] : 0;
        __syncthreads();
        sm[tid] += v;
        __syncthreads();
    }
    if (idx <= NN) ptr[idx] = sm[tid] - x;
    if (tid == SCAN_CHUNK - 1) bsum[blockIdx.x] = sm[tid];
}

__global__ void k_scan2(int* __restrict__ bsum, int* __restrict__ offs) {
    __shared__ int sm[256];
    int tid = threadIdx.x;
    int x = (tid < NBLK_SCAN) ? bsum[tid] : 0;
    sm[tid] = x;
    __syncthreads();
    for (int off = 1; off < 256; off <<= 1) {
        int v = (tid >= off) ? sm[tid - off] : 0;
        __syncthreads();
        sm[tid] += v;
        __syncthreads();
    }
    if (tid < NBLK_SCAN) offs[tid] = sm[tid] - x;
}

__global__ void k_scan3(int* __restrict__ ptr, const int* __restrict__ offs) {
    int idx = blockIdx.x * blockDim.x + threadIdx.x;
    if (idx <= NN) ptr[idx] += offs[idx / SCAN_CHUNK];
}

// fill CSR. user-side slots are [0, ptr[NUM_USER]); src stored ITEM-LOCAL there.
// jit[user_slot] = item-local slot of the same edge (for witem scatter).
__global__ void k_fill(const int* __restrict__ row0, const int* __restrict__ col0,
                       int* __restrict__ pos, const int* __restrict__ ptr,
                       int* __restrict__ srcadj, int* __restrict__ jit,
                       int* __restrict__ jpos1) {
    int e = blockIdx.x * blockDim.x + threadIdx.x;
    if (e >= NE) return;
    int r = row0[e], c = col0[e];
    int ptrU = ptr[NUM_USER];
    int j1 = atomicAdd(&pos[r], 1);   // user-side slot: dst=r, src=c (item-local)
    srcadj[j1] = c - NUM_USER;
    jpos1[e] = j1;
    int j0 = atomicAdd(&pos[c], 1);   // item-side slot: dst=c, src=r
    srcadj[j0] = r;
    jit[j1] = j0 - ptrU;
}

// fill dummy (padding) slots: src=0 (weight is 0 so value harmless)
__global__ void k_pad(const int* __restrict__ cnt, const int* __restrict__ ptr,
                      int* __restrict__ srcadj) {
    int n = blockIdx.x * blockDim.x + threadIdx.x;
    if (n >= NN) return;
    int realend = ptr[n] + cnt[n];
    int end = ptr[n + 1];
    for (int j = realend; j < end; ++j) srcadj[j] = 0;
}

// norm {n, 1/n} per slot + initial weights in both orderings (interleaved
// float4). Real slots only; dummy slots stay 0 from the memsets. No S store:
// softmax(S_old) is always reconstructed from w/n in the conv.
__global__ void k_w0(const float* __restrict__ Sin, const int* __restrict__ row0,
                     const int* __restrict__ col0, const int* __restrict__ jpos1,
                     const int* __restrict__ jit, const float* __restrict__ dinv,
                     float2* __restrict__ norm2, float4* __restrict__ wuA,
                     float4* __restrict__ wiA) {
    int e = blockIdx.x * blockDim.x + threadIdx.x;
    if (e >= NE) return;
    int j = jpos1[e];
    float n = dinv[row0[e]] * dinv[col0[e]];
    float4 s = make_float4(Sin[e], Sin[NE + e], Sin[2 * NE + e], Sin[3 * NE + e]);
    float4 p = softmax4(s);
    norm2[j] = make_float2(n, 1.0f / n);
    float4 w = make_float4(n * p.x, n * p.y, n * p.z, n * p.w);
    wuA[j] = w;
    wiA[jit[j]] = w;
}

// Scur4 (slot order, written by last conv) -> Sout [4][E] original edge order
__global__ void k_sout(const float4* __restrict__ Scur4, const int* __restrict__ jpos1,
                       float* __restrict__ Sout) {
    int e = blockIdx.x * blockDim.x + threadIdx.x;
    if (e >= NE) return;
    float4 s = Scur4[jpos1[e]];
    Sout[e] = s.x;
    Sout[NE + e] = s.y;
    Sout[2 * NE + e] = s.z;
    Sout[3 * NE + e] = s.w;
}

// ---- user conv block macros: 16 outstanding gathers per issue point ----
#define UCONV16(JOFF, TP0) do { \
    int j = beg + (JOFF); \
    int4 sA = *(const int4*)(srcadj + j); \
    int4 sB = *(const int4*)(srcadj + j + 4); \
    int4 sC = *(const int4*)(srcadj + j + 8); \
    int4 sD = *(const int4*)(srcadj + j + 12); \
    unsigned c0 = cmbI[sA.x * DIM + lane]; \
    unsigned c1 = cmbI[sA.y * DIM + lane]; \
    unsigned c2 = cmbI[sA.z * DIM + lane]; \
    unsigned c3 = cmbI[sA.w * DIM + lane]; \
    unsigned c4 = cmbI[sB.x * DIM + lane]; \
    unsigned c5 = cmbI[sB.y * DIM + lane]; \
    unsigned c6 = cmbI[sB.z * DIM + lane]; \
    unsigned c7 = cmbI[sB.w * DIM + lane]; \
    unsigned c8 = cmbI[sC.x * DIM + lane]; \
    unsigned c9 = cmbI[sC.y * DIM + lane]; \
    unsigned c10 = cmbI[sC.z * DIM + lane]; \
    unsigned c11 = cmbI[sC.w * DIM + lane]; \
    unsigned c12 = cmbI[sD.x * DIM + lane]; \
    unsigned c13 = cmbI[sD.y * DIM + lane]; \
    unsigned c14 = cmbI[sD.z * DIM + lane]; \
    unsigned c15 = cmbI[sD.w * DIM + lane]; \
    a0 = fmaf(wuCur[4 * j + k], cvt_lo(c0), a0); \
    a1 = fmaf(wuCur[4 * j + 4 + k], cvt_lo(c1), a1); \
    a2 = fmaf(wuCur[4 * j + 8 + k], cvt_lo(c2), a2); \
    a3 = fmaf(wuCur[4 * j + 12 + k], cvt_lo(c3), a3); \
    a0 = fmaf(wuCur[4 * j + 16 + k], cvt_lo(c4), a0); \
    a1 = fmaf(wuCur[4 * j + 20 + k], cvt_lo(c5), a1); \
    a2 = fmaf(wuCur[4 * j + 24 + k], cvt_lo(c6), a2); \
    a3 = fmaf(wuCur[4 * j + 28 + k], cvt_lo(c7), a3); \
    a0 = fmaf(wuCur[4 * j + 32 + k], cvt_lo(c8), a0); \
    a1 = fmaf(wuCur[4 * j + 36 + k], cvt_lo(c9), a1); \
    a2 = fmaf(wuCur[4 * j + 40 + k], cvt_lo(c10), a2); \
    a3 = fmaf(wuCur[4 * j + 44 + k], cvt_lo(c11), a3); \
    a0 = fmaf(wuCur[4 * j + 48 + k], cvt_lo(c12), a0); \
    a1 = fmaf(wuCur[4 * j + 52 + k], cvt_lo(c13), a1); \
    a2 = fmaf(wuCur[4 * j + 56 + k], cvt_lo(c14), a2); \
    a3 = fmaf(wuCur[4 * j + 60 + k], cvt_lo(c15), a3); \
    tp[(TP0) + 0] = packhi(c0, c1); \
    tp[(TP0) + 1] = packhi(c2, c3); \
    tp[(TP0) + 2] = packhi(c4, c5); \
    tp[(TP0) + 3] = packhi(c6, c7); \
    tp[(TP0) + 4] = packhi(c8, c9); \
    tp[(TP0) + 5] = packhi(c10, c11); \
    tp[(TP0) + 6] = packhi(c12, c13); \
    tp[(TP0) + 7] = packhi(c14, c15); \
} while (0)

#define UCONV8(JOFF, TP0) do { \
    int j = beg + (JOFF); \
    int4 sA = *(const int4*)(srcadj + j); \
    int4 sB = *(const int4*)(srcadj + j + 4); \
    unsigned c0 = cmbI[sA.x * DIM + lane]; \
    unsigned c1 = cmbI[sA.y * DIM + lane]; \
    unsigned c2 = cmbI[sA.z * DIM + lane]; \
    unsigned c3 = cmbI[sA.w * DIM + lane]; \
    unsigned c4 = cmbI[sB.x * DIM + lane]; \
    unsigned c5 = cmbI[sB.y * DIM + lane]; \
    unsigned c6 = cmbI[sB.z * DIM + lane]; \
    unsigned c7 = cmbI[sB.w * DIM + lane]; \
    a0 = fmaf(wuCur[4 * j + k], cvt_lo(c0), a0); \
    a1 = fmaf(wuCur[4 * j + 4 + k], cvt_lo(c1), a1); \
    a2 = fmaf(wuCur[4 * j + 8 + k], cvt_lo(c2), a2); \
    a3 = fmaf(wuCur[4 * j + 12 + k], cvt_lo(c3), a3); \
    a0 = fmaf(wuCur[4 * j + 16 + k], cvt_lo(c4), a0); \
    a1 = fmaf(wuCur[4 * j + 20 + k], cvt_lo(c5), a1); \
    a2 = fmaf(wuCur[4 * j + 24 + k], cvt_lo(c6), a2); \
    a3 = fmaf(wuCur[4 * j + 28 + k], cvt_lo(c7), a3); \
    tp[(TP0) + 0] = packhi(c0, c1); \
    tp[(TP0) + 1] = packhi(c2, c3); \
    tp[(TP0) + 2] = packhi(c4, c5); \
    tp[(TP0) + 3] = packhi(c6, c7); \
} while (0)

#define UCONV4(JOFF, TP0) do { \
    int j = beg + (JOFF); \
    int4 sA = *(const int4*)(srcadj + j); \
    unsigned c0 = cmbI[sA.x * DIM + lane]; \
    unsigned c1 = cmbI[sA.y * DIM + lane]; \
    unsigned c2 = cmbI[sA.z * DIM + lane]; \
    unsigned c3 = cmbI[sA.w * DIM + lane]; \
    a0 = fmaf(wuCur[4 * j + k], cvt_lo(c0), a0); \
    a1 = fmaf(wuCur[4 * j + 4 + k], cvt_lo(c1), a1); \
    a2 = fmaf(wuCur[4 * j + 8 + k], cvt_lo(c2), a2); \
    a3 = fmaf(wuCur[4 * j + 12 + k], cvt_lo(c3), a3); \
    tp[(TP0) + 0] = packhi(c0, c1); \
    tp[(TP0) + 1] = packhi(c2, c3); \
} while (0)

// fused gather conv + routing score + S/weight update.
// wave per node; lane = dim, k = lane>>4 = factor.
// Users: guarded [16][16][8][4] blocks; T register-cached packed 2/VGPR;
// score is pure register math + mixed butterfly; per-slot fused update writes
// NEXT weight buffers (double-buffered vs item readers).
// Items: 16-deep gather loop + 8/4 tails, weights dword-broadcast.
// flags: 1 = layer end (allemb += acc), 4 = write next ego (items: +tanh T)
__global__ __launch_bounds__(256) void k_conv_score(
        const int* __restrict__ ptr, const int* __restrict__ srcadj,
        const float* __restrict__ wuCur, const float* __restrict__ wiCur,
        float* __restrict__ S4f, const float2* __restrict__ norm2,
        const int* __restrict__ jit, float* __restrict__ wuN,
        float* __restrict__ wiN, const unsigned short* __restrict__ egoU,
        const unsigned* __restrict__ cmbI, unsigned short* __restrict__ xnextU,
        unsigned* __restrict__ cmbNext, float* __restrict__ allemb,
        int flags, int last) {
    int node = (blockIdx.x * blockDim.x + threadIdx.x) >> 6;
    int lane = threadIdx.x & 63;
    if (node >= NN) return;
    int beg = __builtin_amdgcn_readfirstlane(ptr[node]);
    int end = __builtin_amdgcn_readfirstlane(ptr[node + 1]);
    int count = end - beg;
    int k = lane >> 4;

    float a0 = 0.0f, a1 = 0.0f, a2 = 0.0f, a3 = 0.0f;

    if (node >= NUM_USER) {
        // ---- item side: conv only, 16-deep ----
        int ptrU = __builtin_amdgcn_readfirstlane(ptr[NUM_USER]);
        const float* wT = wiCur + (size_t)4 * (beg - ptrU);
        int t = 0;
        for (; t + 16 <= count; t += 16) {
            int4 sA = *(const int4*)(srcadj + beg + t);
            int4 sB = *(const int4*)(srcadj + beg + t + 4);
            int4 sC = *(const int4*)(srcadj + beg + t + 8);
            int4 sD = *(const int4*)(srcadj + beg + t + 12);
            a0 = fmaf(wT[4 * t + k], b2f(egoU[sA.x * DIM + lane]), a0);
            a1 = fmaf(wT[4 * t + 4 + k], b2f(egoU[sA.y * DIM + lane]), a1);
            a2 = fmaf(wT[4 * t + 8 + k], b2f(egoU[sA.z * DIM + lane]), a2);
            a3 = fmaf(wT[4 * t + 12 + k], b2f(egoU[sA.w * DIM + lane]), a3);
            a0 = fmaf(wT[4 * t + 16 + k], b2f(egoU[sB.x * DIM + lane]), a0);
            a1 = fmaf(wT[4 * t + 20 + k], b2f(egoU[sB.y * DIM + lane]), a1);
            a2 = fmaf(wT[4 * t + 24 + k], b2f(egoU[sB.z * DIM + lane]), a2);
            a3 = fmaf(wT[4 * t + 28 + k], b2f(egoU[sB.w * DIM + lane]), a3);
            a0 = fmaf(wT[4 * t + 32 + k], b2f(egoU[sC.x * DIM + lane]), a0);
            a1 = fmaf(wT[4 * t + 36 + k], b2f(egoU[sC.y * DIM + lane]), a1);
            a2 = fmaf(wT[4 * t + 40 + k], b2f(egoU[sC.z * DIM + lane]), a2);
            a3 = fmaf(wT[4 * t + 44 + k], b2f(egoU[sC.w * DIM + lane]), a3);
            a0 = fmaf(wT[4 * t + 48 + k], b2f(egoU[sD.x * DIM + lane]), a0);
            a1 = fmaf(wT[4 * t + 52 + k], b2f(egoU[sD.y * DIM + lane]), a1);
            a2 = fmaf(wT[4 * t + 56 + k], b2f(egoU[sD.z * DIM + lane]), a2);
            a3 = fmaf(wT[4 * t + 60 + k], b2f(egoU[sD.w * DIM + lane]), a3);
        }
        if (count & 8) {
            int4 sA = *(const int4*)(srcadj + beg + t);
            int4 sB = *(const int4*)(srcadj + beg + t + 4);
            a0 = fmaf(wT[4 * t + k], b2f(egoU[sA.x * DIM + lane]), a0);
            a1 = fmaf(wT[4 * t + 4 + k], b2f(egoU[sA.y * DIM + lane]), a1);
            a2 = fmaf(wT[4 * t + 8 + k], b2f(egoU[sA.z * DIM + lane]), a2);
            a3 = fmaf(wT[4 * t + 12 + k], b2f(egoU[sA.w * DIM + lane]), a3);
            a0 = fmaf(wT[4 * t + 16 + k], b2f(egoU[sB.x * DIM + lane]), a0);
            a1 = fmaf(wT[4 * t + 20 + k], b2f(egoU[sB.y * DIM + lane]), a1);
            a2 = fmaf(wT[4 * t + 24 + k], b2f(egoU[sB.z * DIM + lane]), a2);
            a3 = fmaf(wT[4 * t + 28 + k], b2f(egoU[sB.w * DIM + lane]), a3);
            t += 8;
        }
        if (count & 4) {
            int4 sA = *(const int4*)(srcadj + beg + t);
            a0 = fmaf(wT[4 * t + k], b2f(egoU[sA.x * DIM + lane]), a0);
            a1 = fmaf(wT[4 * t + 4 + k], b2f(egoU[sA.y * DIM + lane]), a1);
            a2 = fmaf(wT[4 * t + 8 + k], b2f(egoU[sA.z * DIM + lane]), a2);
            a3 = fmaf(wT[4 * t + 12 + k], b2f(egoU[sA.w * DIM + lane]), a3);
        }
        float acc = (a0 + a1) + (a2 + a3);
        if (flags & 1) {
            int i = node * DIM + lane;
            allemb[i] += acc;
            if (flags & 4) {
                float ss = red16(acc * acc);
                float tt = tanhf(acc / fmaxf(sqrtf(ss), 1e-12f));
                cmbNext[i - NUM_USER * DIM] =
                    (((unsigned)f2b(tt)) << 16) | (unsigned)f2b(acc);
            }
        }
        return;
    }

    // ---- user side: conv + routing score + fused S/w update ----
    unsigned tp[22];          // packed T cache: 2 slots/word, static-indexed
    bool big = count > MAXU_SLOTS;   // wave-uniform fallback (statistically never)
    int rem = count & 15;
    int rbase = count & ~15;

    if (!big) {
        if (count >= 16) UCONV16(0, 0);
        if (count >= 32) UCONV16(16, 8);
        if (rem & 8) UCONV8(rbase, 16);
        if (rem & 4) UCONV4(rbase + (rem & 8), 20);
    } else {
        for (int j = beg; j < end; j += 4) {
            int4 s = *(const int4*)(srcadj + j);
            a0 = fmaf(wuCur[4 * j + k], cvt_lo(cmbI[s.x * DIM + lane]), a0);
            a1 = fmaf(wuCur[4 * j + 4 + k], cvt_lo(cmbI[s.y * DIM + lane]), a1);
            a2 = fmaf(wuCur[4 * j + 8 + k], cvt_lo(cmbI[s.z * DIM + lane]), a2);
            a3 = fmaf(wuCur[4 * j + 12 + k], cvt_lo(cmbI[s.w * DIM + lane]), a3);
        }
    }
    float acc = (a0 + a1) + (a2 + a3);

    if (flags & 1) {
        int i = node * DIM + lane;
        allemb[i] += acc;
        if (flags & 4) xnextU[i] = f2b(acc);
    }

    // routing score from register cache + fused per-slot S/weight update
    float ssu = red16(acc * acc);
    float u = acc / fmaxf(sqrtf(ssu), 1e-12f);
    bool b0 = lane & 1;
    bool b1 = lane & 2;
    bool b2 = lane & 4;
    bool b3 = lane & 8;

    if (!big) {
#define USC16(JOFF, TP0) do { \
        int j = beg + (JOFF); \
        float p0 = u * __uint_as_float(tp[(TP0) + 0] << 16); \
        float p1 = u * __uint_as_float(tp[(TP0) + 0] & 0xffff0000u); \
        float p2 = u * __uint_as_float(tp[(TP0) + 1] << 16); \
        float p3 = u * __uint_as_float(tp[(TP0) + 1] & 0xffff0000u); \
        float p4 = u * __uint_as_float(tp[(TP0) + 2] << 16); \
        float p5 = u * __uint_as_float(tp[(TP0) + 2] & 0xffff0000u); \
        float p6 = u * __uint_as_float(tp[(TP0) + 3] << 16); \
        float p7 = u * __uint_as_float(tp[(TP0) + 3] & 0xffff0000u); \
        float p8 = u * __uint_as_float(tp[(TP0) + 4] << 16); \
        float p9 = u * __uint_as_float(tp[(TP0) + 4] & 0xffff0000u); \
        float p10 = u * __uint_as_float(tp[(TP0) + 5] << 16); \
        float p11 = u * __uint_as_float(tp[(TP0) + 5] & 0xffff0000u); \
        float p12 = u * __uint_as_float(tp[(TP0) + 6] << 16); \
        float p13 = u * __uint_as_float(tp[(TP0) + 6] & 0xffff0000u); \
        float p14 = u * __uint_as_float(tp[(TP0) + 7] << 16); \
        float p15 = u * __uint_as_float(tp[(TP0) + 7] & 0xffff0000u); \
        float q0 = mixv(p0, p1, b0, 1); \
        float q1 = mixv(p2, p3, b0, 1); \
        float q2 = mixv(p4, p5, b0, 1); \
        float q3 = mixv(p6, p7, b0, 1); \
        float q4 = mixv(p8, p9, b0, 1); \
        float q5 = mixv(p10, p11, b0, 1); \
        float q6 = mixv(p12, p13, b0, 1); \
        float q7 = mixv(p14, p15, b0, 1); \
        float r0 = mixv(q0, q1, b1, 2); \
        float r1 = mixv(q2, q3, b1, 2); \
        float r2 = mixv(q4, q5, b1, 2); \
        float r3 = mixv(q6, q7, b1, 2); \
        float s0 = mixv(r0, r1, b2, 4); \
        float s1 = mixv(r2, r3, b2, 4); \
        float t0 = mixv(s0, s1, b3, 8); \
        fused_upd(j + (lane & 15), k, t0, true, \
                  wuCur, S4f, norm2, jit, wuN, wiN, last); \
} while (0)
        if (count >= 16) USC16(0, 0);
        if (count >= 32) USC16(16, 8);
        if (rem & 8) {
            int j = beg + rbase;
            float p0 = u * __uint_as_float(tp[16] << 16);
            float p1 = u * __uint_as_float(tp[16] & 0xffff0000u);
            float p2 = u * __uint_as_float(tp[17] << 16);
            float p3 = u * __uint_as_float(tp[17] & 0xffff0000u);
            float p4 = u * __uint_as_float(tp[18] << 16);
            float p5 = u * __uint_as_float(tp[18] & 0xffff0000u);
            float p6 = u * __uint_as_float(tp[19] << 16);
            float p7 = u * __uint_as_float(tp[19] & 0xffff0000u);
            float q0 = mixv(p0, p1, b0, 1);
            float q1 = mixv(p2, p3, b0, 1);
            float q2 = mixv(p4, p5, b0, 1);
            float q3 = mixv(p6, p7, b0, 1);
            float r0 = mixv(q0, q1, b1, 2);
            float r1 = mixv(q2, q3, b1, 2);
            float t0 = mixv(r0, r1, b2, 4);
            t0 += __shfl_xor(t0, 8);
            fused_upd(j + (lane & 7), k, t0, !(lane & 8),
                      wuCur, S4f, norm2, jit, wuN, wiN, last);
        }
        if (rem & 4) {
            int j = beg + rbase + (rem & 8);
            float p0 = u * __uint_as_float(tp[20] << 16);
            float p1 = u * __uint_as_float(tp[20] & 0xffff0000u);
            float p2 = u * __uint_as_float(tp[21] << 16);
            float p3 = u * __uint_as_float(tp[21] & 0xffff0000u);
            float q0 = mixv(p0, p1, b0, 1);
            float q1 = mixv(p2, p3, b0, 1);
            float r0 = mixv(q0, q1, b1, 2);
            r0 += __shfl_xor(r0, 4);
            r0 += __shfl_xor(r0, 8);
            fused_upd(j + (lane & 3), k, r0, !(lane & 12),
                      wuCur, S4f, norm2, jit, wuN, wiN, last);
        }
    } else {
        for (int j = beg; j < end; j += 4) {
            int4 s = *(const int4*)(srcadj + j);
            float p0 = red16(u * cvt_hi(cmbI[s.x * DIM + lane]));
            float p1 = red16(u * cvt_hi(cmbI[s.y * DIM + lane]));
            float p2 = red16(u * cvt_hi(cmbI[s.z * DIM + lane]));
            float p3 = red16(u * cvt_hi(cmbI[s.w * DIM + lane]));
            int sl = lane & 3;
            float dv = p0;
            dv = (sl == 1) ? p1 : dv;
            dv = (sl == 2) ? p2 : dv;
            dv = (sl == 3) ? p3 : dv;
            fused_upd(j + sl, k, dv, !(lane & 12),
                      wuCur, S4f, norm2, jit, wuN, wiN, last);
        }
    }
}

extern "C" void kernel_launch(void* const* d_in, const int* in_sizes, int n_in,
                              void* d_out, int out_size, void* d_ws, size_t ws_size,
                              hipStream_t stream) {
    const float* user = (const float*)d_in[0];
    const float* item = (const float*)d_in[1];
    const float* S_in = (const float*)d_in[2];
    const int* edge = (const int*)d_in[3];
    const int* row0 = edge;
    const int* col0 = edge + NE;

    float* out = (float*)d_out;
    float* allemb = out;              // NN*DIM floats
    float* Sfinal = out + NN * DIM;   // KF*NE floats

    char* ws = (char*)d_ws;
    size_t off = 0;
    auto carve = [&](size_t bytes) { void* p = ws + off; off += (bytes + 255) & ~(size_t)255; return p; };
    int* cnt = (int*)carve((NN + 1) * sizeof(int));
    int* cntp = (int*)carve((NN + 1) * sizeof(int));
    int* ptr = (int*)carve((NN + 1) * sizeof(int));
    int* pos = (int*)carve((NN + 1) * sizeof(int));
    int* bsum = (int*)carve(256 * sizeof(int));
    int* offs = (int*)carve(256 * sizeof(int));
    int* srcadj = (int*)carve((size_t)(NEPU_MAX + NEPI_MAX) * sizeof(int));
    int* jit = (int*)carve((size_t)NEPU_MAX * sizeof(int));
    int* jpos1 = (int*)carve((size_t)NE * sizeof(int));
    float* dinv = (float*)carve(NN * sizeof(float));
    float2* norm2 = (float2*)carve((size_t)NEPU_MAX * sizeof(float2));
    float4* Scur4 = (float4*)carve((size_t)NEPU_MAX * sizeof(float4));
    float4* wuA = (float4*)carve((size_t)NEPU_MAX * sizeof(float4));
    float4* wuB = (float4*)carve((size_t)NEPU_MAX * sizeof(float4));
    float4* wiA = (float4*)carve((size_t)NEPI_MAX * sizeof(float4));
    float4* wiB = (float4*)carve((size_t)NEPI_MAX * sizeof(float4));
    unsigned short* egoUA = (unsigned short*)carve((size_t)NUM_USER * DIM * 2);
    unsigned short* egoUB = (unsigned short*)carve((size_t)NUM_USER * DIM * 2);
    unsigned* cmbIA = (unsigned*)carve((size_t)NUM_ITEM * DIM * 4);
    unsigned* cmbIB = (unsigned*)carve((size_t)NUM_ITEM * DIM * 4);

    hipMemsetAsync(cnt, 0, (NN + 1) * sizeof(int), stream);
    hipMemsetAsync(norm2, 0, (size_t)NEPU_MAX * sizeof(float2), stream);
    hipMemsetAsync(wuA, 0, (size_t)NEPU_MAX * sizeof(float4), stream);
    hipMemsetAsync(wuB, 0, (size_t)NEPU_MAX * sizeof(float4), stream);
    hipMemsetAsync(wiA, 0, (size_t)NEPI_MAX * sizeof(float4), stream);
    hipMemsetAsync(wiB, 0, (size_t)NEPI_MAX * sizeof(float4), stream);

    k_count<<<(NE + 255) / 256, 256, 0, stream>>>(row0, col0, cnt);
    k_dinv_pad<<<(NN + 255) / 256, 256, 0, stream>>>(cnt, dinv, cntp);
    k_scan1<<<NBLK_SCAN, SCAN_CHUNK, 0, stream>>>(cntp, ptr, bsum);
    k_scan2<<<1, 256, 0, stream>>>(bsum, offs);
    k_scan3<<<(NN + 1 + 255) / 256, 256, 0, stream>>>(ptr, offs);
    hipMemcpyAsync(pos, ptr, (NN + 1) * sizeof(int), hipMemcpyDeviceToDevice, stream);
    k_fill<<<(NE + 255) / 256, 256, 0, stream>>>(row0, col0, pos, ptr, srcadj, jit, jpos1);
    k_pad<<<(NN + 255) / 256, 256, 0, stream>>>(cnt, ptr, srcadj);
    k_w0<<<(NE + 255) / 256, 256, 0, stream>>>(S_in, row0, col0, jpos1, jit, dinv,
                                               norm2, wuA, wiA);
    k_init<<<(NN * 64 + 255) / 256, 256, 0, stream>>>(user, item, egoUA, cmbIA, allemb);

    unsigned short* egoU = egoUA;
    unsigned short* egoUn = egoUB;
    unsigned* cmbI = cmbIA;
    unsigned* cmbIn = cmbIB;
    float* wuCur = (float*)wuA;
    float* wuNxt = (float*)wuB;
    float* wiCur = (float*)wiA;
    float* wiNxt = (float*)wiB;
    for (int layer = 0; layer < 2; ++layer) {
        for (int it = 0; it < 2; ++it) {
            int flags = 0;
            if (it == 1) flags |= 1;                   // layer end: allemb += acc
            if (it == 1 && layer == 0) flags |= 4;     // write next ego (+item T)
            int last = (layer == 1 && it == 1) ? 1 : 0;
            k_conv_score<<<(NN * 64 + 255) / 256, 256, 0, stream>>>(
                ptr, srcadj, wuCur, wiCur, (float*)Scur4, norm2, jit,
                wuNxt, wiNxt, egoU, cmbI, egoUn, cmbIn, allemb, flags, last);
            float* t = wuCur; wuCur = wuNxt; wuNxt = t;
            t = wiCur; wiCur = wiNxt; wiNxt = t;
        }
        unsigned short* t = egoU; egoU = egoUn; egoUn = t;
        unsigned* tc = cmbI; cmbI = cmbIn; cmbIn = tc;
    }
    k_sout<<<(NE + 255) / 256, 256, 0, stream>>>(Scur4, jpos1, Sfinal);
}

// Round 5
// 440.919 us; speedup vs baseline: 1.2749x; 1.0218x over previous
//
#include <hip/hip_runtime.h>

#define NUM_USER 60000
#define NUM_ITEM 40000
#define NN 100000
#define NE 500000
#define DIM 64
#define KF 4
#define SCAN_CHUNK 512
#define NBLK_SCAN ((NN + 1 + SCAN_CHUNK - 1) / SCAN_CHUNK)
// padded slot-count upper bounds (each node rounds up to multiple of 4)
#define NEPU_MAX (NE + 3 * NUM_USER)   // 680000 user-side slots max
#define NEPI_MAX (NE + 3 * NUM_ITEM)   // 620000 item-side slots max
#define MAXU_SLOTS 44                  // register-cached user path handles <=44 slots

// sum within each 16-lane group (butterfly: all lanes get result)
__device__ __forceinline__ float red16(float v) {
    v += __shfl_xor(v, 1);
    v += __shfl_xor(v, 2);
    v += __shfl_xor(v, 4);
    v += __shfl_xor(v, 8);
    return v;
}

__device__ __forceinline__ float b2f(unsigned short u) {
    return __uint_as_float(((unsigned)u) << 16);
}
__device__ __forceinline__ unsigned short f2b(float x) {
    unsigned u = __float_as_uint(x);
    u = (u + 0x7fffu + ((u >> 16) & 1u)) >> 16;   // RNE
    return (unsigned short)u;
}
// combined item word: high16 = T (bf16 bits), low16 = ego (bf16 bits)
__device__ __forceinline__ float cvt_lo(unsigned c) { return __uint_as_float(c << 16); }
__device__ __forceinline__ float cvt_hi(unsigned c) { return __uint_as_float(c & 0xffff0000u); }
// pack hi16 halves of two combined words: lo16(out)=hi16(c0), hi16(out)=hi16(c1)
__device__ __forceinline__ unsigned packhi(unsigned c0, unsigned c1) {
#if defined(__has_builtin) && __has_builtin(__builtin_amdgcn_perm)
    return __builtin_amdgcn_perm(c1, c0, 0x07060302u);
#else
    return (c0 >> 16) | (c1 & 0xffff0000u);
#endif
}
// mixed-butterfly level: lane keeps the value whose slot-bit matches its lane bit
__device__ __forceinline__ float mixv(float x, float y, bool b, int m) {
    return (b ? y : x) + __shfl_xor(b ? x : y, m);
}

__device__ __forceinline__ float4 softmax4(float4 s) {
    float m = fmaxf(fmaxf(s.x, s.y), fmaxf(s.z, s.w));
    float e0 = __expf(s.x - m), e1 = __expf(s.y - m);
    float e2 = __expf(s.z - m), e3 = __expf(s.w - m);
    float inv = 1.0f / (e0 + e1 + e2 + e3);
    return make_float4(e0 * inv, e1 * inv, e2 * inv, e3 * inv);
}

// Fused per-slot S/weight update. Lane holds dot for (slot jj, factor k);
// factor partners are lanes 16 apart. softmax(S_old) is reconstructed as
// w_cur * (1/n)  (w_cur is L1-hot from the conv loop) -- no S state traffic.
// snew = w*rn + dot; last: S4f <- snew (final output);
// else: w' = n * softmax_k(snew) -> wuN, wiN (dummy slots n=0: skipped).
__device__ __forceinline__ void fused_upd(int jj, int k, float dot, bool wr,
        const float* __restrict__ wuCur, float* __restrict__ S4f,
        const float2* __restrict__ norm2, const int* __restrict__ jit,
        float* __restrict__ wuN, float* __restrict__ wiN, int last) {
    float w = wuCur[4 * jj + k];
    float2 nn = norm2[jj];
    float snew = fmaf(w, nn.y, dot);
    if (last) {
        if (wr) S4f[4 * jj + k] = snew;
        return;
    }
    float m2 = fmaxf(snew, __shfl_xor(snew, 16));
    m2 = fmaxf(m2, __shfl_xor(m2, 32));
    float e2 = __expf(snew - m2);
    float s2 = e2 + __shfl_xor(e2, 16);
    s2 += __shfl_xor(s2, 32);
    if (wr && nn.x > 0.0f) {
        float wn = nn.x * e2 * (1.0f / s2);
        wuN[4 * jj + k] = wn;
        wiN[4 * jit[jj] + k] = wn;
    }
}

// wave per node. Users: egoU(bf16) + allemb. Items: cmbI = (tanh(l2n16)<<16)|ego.
__global__ void k_init(const float* __restrict__ user, const float* __restrict__ item,
                       unsigned short* __restrict__ egoU, unsigned* __restrict__ cmbI,
                       float* __restrict__ allemb) {
    int node = (blockIdx.x * blockDim.x + threadIdx.x) >> 6;
    int lane = threadIdx.x & 63;
    if (node >= NN) return;
    int i = node * DIM + lane;
    if (node < NUM_USER) {
        float v = user[i];
        egoU[i] = f2b(v);
        allemb[i] = v;
    } else {
        float v = item[i - NUM_USER * DIM];
        allemb[i] = v;
        float ss = red16(v * v);
        float t = tanhf(v / fmaxf(sqrtf(ss), 1e-12f));
        cmbI[i - NUM_USER * DIM] = (((unsigned)f2b(t)) << 16) | (unsigned)f2b(v);
    }
}

__global__ void k_count(const int* __restrict__ row0, const int* __restrict__ col0,
                        int* __restrict__ cnt) {
    int e = blockIdx.x * blockDim.x + threadIdx.x;
    if (e >= NE) return;
    atomicAdd(&cnt[row0[e]], 1);
    atomicAdd(&cnt[col0[e]], 1);
}

// dinv + padded counts (round degree up to multiple of 4)
__global__ void k_dinv_pad(const int* __restrict__ cnt, float* __restrict__ dinv,
                           int* __restrict__ cntp) {
    int i = blockIdx.x * blockDim.x + threadIdx.x;
    if (i >= NN) return;
    int d = cnt[i];
    dinv[i] = (d > 0) ? rsqrtf((float)d) : 0.0f;
    cntp[i] = (d + 3) & ~3;
}

// --- 3-stage exclusive scan over cntp[NN] -> ptr[NN+1] ---
__global__ void k_scan1(const int* __restrict__ cnt, int* __restrict__ ptr,
                        int* __restrict__ bsum) {
    __shared__ int sm[SCAN_CHUNK];
    int tid = threadIdx.x;
    int idx = blockIdx.x * SCAN_CHUNK + tid;
    int x = (idx < NN) ? cnt[idx] : 0;
    sm[tid] = x;
    __syncthreads();
    for (int off = 1; off < SCAN_CHUNK; off <<= 1) {
        int v = (tid >= off) ? sm[tid - off] : 0;
        __syncthreads();
        sm[tid] += v;
        __syncthreads();
    }
    if (idx <= NN) ptr[idx] = sm[tid] - x;
    if (tid == SCAN_CHUNK - 1) bsum[blockIdx.x] = sm[tid];
}

__global__ void k_scan2(int* __restrict__ bsum, int* __restrict__ offs) {
    __shared__ int sm[256];
    int tid = threadIdx.x;
    int x = (tid < NBLK_SCAN) ? bsum[tid] : 0;
    sm[tid] = x;
    __syncthreads();
    for (int off = 1; off < 256; off <<= 1) {
        int v = (tid >= off) ? sm[tid - off] : 0;
        __syncthreads();
        sm[tid] += v;
        __syncthreads();
    }
    if (tid < NBLK_SCAN) offs[tid] = sm[tid] - x;
}

// finalize scan; also replicate into pos (removes the D2D memcpy dispatch)
__global__ void k_scan3(int* __restrict__ ptr, const int* __restrict__ offs,
                        int* __restrict__ pos) {
    int idx = blockIdx.x * blockDim.x + threadIdx.x;
    if (idx > NN) return;
    int v = ptr[idx] + offs[idx / SCAN_CHUNK];
    ptr[idx] = v;
    pos[idx] = v;
}

// fill CSR. user-side slots are [0, ptr[NUM_USER]); src stored ITEM-LOCAL,
// PRE-SCALED by DIM (<<6). jit[user_slot] = item-local slot of same edge;
// einv[user_slot] = edge id (for slot-parallel k_w0).
__global__ void k_fill(const int* __restrict__ row0, const int* __restrict__ col0,
                       int* __restrict__ pos, const int* __restrict__ ptr,
                       int* __restrict__ srcadj, int* __restrict__ jit,
                       int* __restrict__ jpos1, int* __restrict__ einv) {
    int e = blockIdx.x * blockDim.x + threadIdx.x;
    if (e >= NE) return;
    int r = row0[e], c = col0[e];
    int ptrU = ptr[NUM_USER];
    int j1 = atomicAdd(&pos[r], 1);   // user-side slot: dst=r, src=c (item-local)
    srcadj[j1] = (c - NUM_USER) << 6;
    jpos1[e] = j1;
    einv[j1] = e;
    int j0 = atomicAdd(&pos[c], 1);   // item-side slot: dst=c, src=r
    srcadj[j0] = r << 6;
    jit[j1] = j0 - ptrU;
}

// dummy (padding) slots: src=0, einv=-1, zero weights/norm in all buffers
// (replaces the big full-buffer memsets)
__global__ void k_pad(const int* __restrict__ cnt, const int* __restrict__ ptr,
                      int* __restrict__ srcadj, int* __restrict__ einv,
                      float2* __restrict__ norm2, float4* __restrict__ wuA,
                      float4* __restrict__ wuB, float4* __restrict__ wiA,
                      float4* __restrict__ wiB) {
    int n = blockIdx.x * blockDim.x + threadIdx.x;
    if (n >= NN) return;
    int realend = ptr[n] + cnt[n];
    int end = ptr[n + 1];
    int ptrU = ptr[NUM_USER];
    float4 z4 = make_float4(0.f, 0.f, 0.f, 0.f);
    for (int j = realend; j < end; ++j) {
        srcadj[j] = 0;
        if (n < NUM_USER) {
            einv[j] = -1;
            norm2[j] = make_float2(0.f, 0.f);
            wuA[j] = z4;
            wuB[j] = z4;
        } else {
            wiA[j - ptrU] = z4;
            wiB[j - ptrU] = z4;
        }
    }
}

// slot-parallel init: norm {n,1/n} + initial weights in both orderings.
// Coalesced writes for norm2/wuA; random reads are L3-absorbed.
__global__ void k_w0(const float* __restrict__ Sin, const int* __restrict__ row0,
                     const int* __restrict__ col0, const int* __restrict__ einv,
                     const int* __restrict__ jit, const float* __restrict__ dinv,
                     const int* __restrict__ ptr, float2* __restrict__ norm2,
                     float4* __restrict__ wuA, float4* __restrict__ wiA) {
    int j = blockIdx.x * blockDim.x + threadIdx.x;
    if (j >= ptr[NUM_USER]) return;
    int e = einv[j];
    if (e < 0) return;   // dummy: zeroed by k_pad
    float n = dinv[row0[e]] * dinv[col0[e]];
    float4 s = make_float4(Sin[e], Sin[NE + e], Sin[2 * NE + e], Sin[3 * NE + e]);
    float4 p = softmax4(s);
    norm2[j] = make_float2(n, 1.0f / n);
    float4 w = make_float4(n * p.x, n * p.y, n * p.z, n * p.w);
    wuA[j] = w;
    wiA[jit[j]] = w;
}

// Scur4 (slot order, written by last conv) -> Sout [4][E] original edge order
__global__ void k_sout(const float4* __restrict__ Scur4, const int* __restrict__ jpos1,
                       float* __restrict__ Sout) {
    int e = blockIdx.x * blockDim.x + threadIdx.x;
    if (e >= NE) return;
    float4 s = Scur4[jpos1[e]];
    Sout[e] = s.x;
    Sout[NE + e] = s.y;
    Sout[2 * NE + e] = s.z;
    Sout[3 * NE + e] = s.w;
}

// ---- user conv block macros: 16 outstanding gathers per issue point ----
// (srcadj values are pre-scaled by DIM)
#define UCONV16(JOFF, TP0) do { \
    int j = beg + (JOFF); \
    int4 sA = *(const int4*)(srcadj + j); \
    int4 sB = *(const int4*)(srcadj + j + 4); \
    int4 sC = *(const int4*)(srcadj + j + 8); \
    int4 sD = *(const int4*)(srcadj + j + 12); \
    unsigned c0 = cmbI[sA.x + lane]; \
    unsigned c1 = cmbI[sA.y + lane]; \
    unsigned c2 = cmbI[sA.z + lane]; \
    unsigned c3 = cmbI[sA.w + lane]; \
    unsigned c4 = cmbI[sB.x + lane]; \
    unsigned c5 = cmbI[sB.y + lane]; \
    unsigned c6 = cmbI[sB.z + lane]; \
    unsigned c7 = cmbI[sB.w + lane]; \
    unsigned c8 = cmbI[sC.x + lane]; \
    unsigned c9 = cmbI[sC.y + lane]; \
    unsigned c10 = cmbI[sC.z + lane]; \
    unsigned c11 = cmbI[sC.w + lane]; \
    unsigned c12 = cmbI[sD.x + lane]; \
    unsigned c13 = cmbI[sD.y + lane]; \
    unsigned c14 = cmbI[sD.z + lane]; \
    unsigned c15 = cmbI[sD.w + lane]; \
    a0 = fmaf(wuCur[4 * j + k], cvt_lo(c0), a0); \
    a1 = fmaf(wuCur[4 * j + 4 + k], cvt_lo(c1), a1); \
    a2 = fmaf(wuCur[4 * j + 8 + k], cvt_lo(c2), a2); \
    a3 = fmaf(wuCur[4 * j + 12 + k], cvt_lo(c3), a3); \
    a0 = fmaf(wuCur[4 * j + 16 + k], cvt_lo(c4), a0); \
    a1 = fmaf(wuCur[4 * j + 20 + k], cvt_lo(c5), a1); \
    a2 = fmaf(wuCur[4 * j + 24 + k], cvt_lo(c6), a2); \
    a3 = fmaf(wuCur[4 * j + 28 + k], cvt_lo(c7), a3); \
    a0 = fmaf(wuCur[4 * j + 32 + k], cvt_lo(c8), a0); \
    a1 = fmaf(wuCur[4 * j + 36 + k], cvt_lo(c9), a1); \
    a2 = fmaf(wuCur[4 * j + 40 + k], cvt_lo(c10), a2); \
    a3 = fmaf(wuCur[4 * j + 44 + k], cvt_lo(c11), a3); \
    a0 = fmaf(wuCur[4 * j + 48 + k], cvt_lo(c12), a0); \
    a1 = fmaf(wuCur[4 * j + 52 + k], cvt_lo(c13), a1); \
    a2 = fmaf(wuCur[4 * j + 56 + k], cvt_lo(c14), a2); \
    a3 = fmaf(wuCur[4 * j + 60 + k], cvt_lo(c15), a3); \
    tp[(TP0) + 0] = packhi(c0, c1); \
    tp[(TP0) + 1] = packhi(c2, c3); \
    tp[(TP0) + 2] = packhi(c4, c5); \
    tp[(TP0) + 3] = packhi(c6, c7); \
    tp[(TP0) + 4] = packhi(c8, c9); \
    tp[(TP0) + 5] = packhi(c10, c11); \
    tp[(TP0) + 6] = packhi(c12, c13); \
    tp[(TP0) + 7] = packhi(c14, c15); \
} while (0)

#define UCONV8(JOFF, TP0) do { \
    int j = beg + (JOFF); \
    int4 sA = *(const int4*)(srcadj + j); \
    int4 sB = *(const int4*)(srcadj + j + 4); \
    unsigned c0 = cmbI[sA.x + lane]; \
    unsigned c1 = cmbI[sA.y + lane]; \
    unsigned c2 = cmbI[sA.z + lane]; \
    unsigned c3 = cmbI[sA.w + lane]; \
    unsigned c4 = cmbI[sB.x + lane]; \
    unsigned c5 = cmbI[sB.y + lane]; \
    unsigned c6 = cmbI[sB.z + lane]; \
    unsigned c7 = cmbI[sB.w + lane]; \
    a0 = fmaf(wuCur[4 * j + k], cvt_lo(c0), a0); \
    a1 = fmaf(wuCur[4 * j + 4 + k], cvt_lo(c1), a1); \
    a2 = fmaf(wuCur[4 * j + 8 + k], cvt_lo(c2), a2); \
    a3 = fmaf(wuCur[4 * j + 12 + k], cvt_lo(c3), a3); \
    a0 = fmaf(wuCur[4 * j + 16 + k], cvt_lo(c4), a0); \
    a1 = fmaf(wuCur[4 * j + 20 + k], cvt_lo(c5), a1); \
    a2 = fmaf(wuCur[4 * j + 24 + k], cvt_lo(c6), a2); \
    a3 = fmaf(wuCur[4 * j + 28 + k], cvt_lo(c7), a3); \
    tp[(TP0) + 0] = packhi(c0, c1); \
    tp[(TP0) + 1] = packhi(c2, c3); \
    tp[(TP0) + 2] = packhi(c4, c5); \
    tp[(TP0) + 3] = packhi(c6, c7); \
} while (0)

#define UCONV4(JOFF, TP0) do { \
    int j = beg + (JOFF); \
    int4 sA = *(const int4*)(srcadj + j); \
    unsigned c0 = cmbI[sA.x + lane]; \
    unsigned c1 = cmbI[sA.y + lane]; \
    unsigned c2 = cmbI[sA.z + lane]; \
    unsigned c3 = cmbI[sA.w + lane]; \
    a0 = fmaf(wuCur[4 * j + k], cvt_lo(c0), a0); \
    a1 = fmaf(wuCur[4 * j + 4 + k], cvt_lo(c1), a1); \
    a2 = fmaf(wuCur[4 * j + 8 + k], cvt_lo(c2), a2); \
    a3 = fmaf(wuCur[4 * j + 12 + k], cvt_lo(c3), a3); \
    tp[(TP0) + 0] = packhi(c0, c1); \
    tp[(TP0) + 1] = packhi(c2, c3); \
} while (0)

// fused gather conv + routing score + S/weight update.
// wave per node; lane = dim, k = lane>>4 = factor.
// nlim: NUM_USER on non-layer-end dispatches (item conv output is unused
// there -- the routing update only needs user x_new and layer-start item T),
// NN on layer-end dispatches.
// flags: 1 = layer end (allemb += acc), 4 = write next ego (items: +tanh T)
__global__ __launch_bounds__(256) void k_conv_score(
        const int* __restrict__ ptr, const int* __restrict__ srcadj,
        const float* __restrict__ wuCur, const float* __restrict__ wiCur,
        float* __restrict__ S4f, const float2* __restrict__ norm2,
        const int* __restrict__ jit, float* __restrict__ wuN,
        float* __restrict__ wiN, const unsigned short* __restrict__ egoU,
        const unsigned* __restrict__ cmbI, unsigned short* __restrict__ xnextU,
        unsigned* __restrict__ cmbNext, float* __restrict__ allemb,
        int flags, int last, int nlim) {
    int node = (blockIdx.x * blockDim.x + threadIdx.x) >> 6;
    int lane = threadIdx.x & 63;
    if (node >= nlim) return;
    int beg = __builtin_amdgcn_readfirstlane(ptr[node]);
    int end = __builtin_amdgcn_readfirstlane(ptr[node + 1]);
    int count = end - beg;
    int k = lane >> 4;

    float a0 = 0.0f, a1 = 0.0f, a2 = 0.0f, a3 = 0.0f;

    if (node >= NUM_USER) {
        // ---- item side: conv only, 16-deep (runs only on layer-end) ----
        int ptrU = __builtin_amdgcn_readfirstlane(ptr[NUM_USER]);
        const float* wT = wiCur + (size_t)4 * (beg - ptrU);
        int t = 0;
        for (; t + 16 <= count; t += 16) {
            int4 sA = *(const int4*)(srcadj + beg + t);
            int4 sB = *(const int4*)(srcadj + beg + t + 4);
            int4 sC = *(const int4*)(srcadj + beg + t + 8);
            int4 sD = *(const int4*)(srcadj + beg + t + 12);
            a0 = fmaf(wT[4 * t + k], b2f(egoU[sA.x + lane]), a0);
            a1 = fmaf(wT[4 * t + 4 + k], b2f(egoU[sA.y + lane]), a1);
            a2 = fmaf(wT[4 * t + 8 + k], b2f(egoU[sA.z + lane]), a2);
            a3 = fmaf(wT[4 * t + 12 + k], b2f(egoU[sA.w + lane]), a3);
            a0 = fmaf(wT[4 * t + 16 + k], b2f(egoU[sB.x + lane]), a0);
            a1 = fmaf(wT[4 * t + 20 + k], b2f(egoU[sB.y + lane]), a1);
            a2 = fmaf(wT[4 * t + 24 + k], b2f(egoU[sB.z + lane]), a2);
            a3 = fmaf(wT[4 * t + 28 + k], b2f(egoU[sB.w + lane]), a3);
            a0 = fmaf(wT[4 * t + 32 + k], b2f(egoU[sC.x + lane]), a0);
            a1 = fmaf(wT[4 * t + 36 + k], b2f(egoU[sC.y + lane]), a1);
            a2 = fmaf(wT[4 * t + 40 + k], b2f(egoU[sC.z + lane]), a2);
            a3 = fmaf(wT[4 * t + 44 + k], b2f(egoU[sC.w + lane]), a3);
            a0 = fmaf(wT[4 * t + 48 + k], b2f(egoU[sD.x + lane]), a0);
            a1 = fmaf(wT[4 * t + 52 + k], b2f(egoU[sD.y + lane]), a1);
            a2 = fmaf(wT[4 * t + 56 + k], b2f(egoU[sD.z + lane]), a2);
            a3 = fmaf(wT[4 * t + 60 + k], b2f(egoU[sD.w + lane]), a3);
        }
        if (count & 8) {
            int4 sA = *(const int4*)(srcadj + beg + t);
            int4 sB = *(const int4*)(srcadj + beg + t + 4);
            a0 = fmaf(wT[4 * t + k], b2f(egoU[sA.x + lane]), a0);
            a1 = fmaf(wT[4 * t + 4 + k], b2f(egoU[sA.y + lane]), a1);
            a2 = fmaf(wT[4 * t + 8 + k], b2f(egoU[sA.z + lane]), a2);
            a3 = fmaf(wT[4 * t + 12 + k], b2f(egoU[sA.w + lane]), a3);
            a0 = fmaf(wT[4 * t + 16 + k], b2f(egoU[sB.x + lane]), a0);
            a1 = fmaf(wT[4 * t + 20 + k], b2f(egoU[sB.y + lane]), a1);
            a2 = fmaf(wT[4 * t + 24 + k], b2f(egoU[sB.z + lane]), a2);
            a3 = fmaf(wT[4 * t + 28 + k], b2f(egoU[sB.w + lane]), a3);
            t += 8;
        }
        if (count & 4) {
            int4 sA = *(const int4*)(srcadj + beg + t);
            a0 = fmaf(wT[4 * t + k], b2f(egoU[sA.x + lane]), a0);
            a1 = fmaf(wT[4 * t + 4 + k], b2f(egoU[sA.y + lane]), a1);
            a2 = fmaf(wT[4 * t + 8 + k], b2f(egoU[sA.z + lane]), a2);
            a3 = fmaf(wT[4 * t + 12 + k], b2f(egoU[sA.w + lane]), a3);
        }
        float acc = (a0 + a1) + (a2 + a3);
        if (flags & 1) {
            int i = node * DIM + lane;
            allemb[i] += acc;
            if (flags & 4) {
                float ss = red16(acc * acc);
                float tt = tanhf(acc / fmaxf(sqrtf(ss), 1e-12f));
                cmbNext[i - NUM_USER * DIM] =
                    (((unsigned)f2b(tt)) << 16) | (unsigned)f2b(acc);
            }
        }
        return;
    }

    // ---- user side: conv + routing score + fused S/w update ----
    unsigned tp[22];          // packed T cache: 2 slots/word, static-indexed
    bool big = count > MAXU_SLOTS;   // wave-uniform fallback (statistically never)
    int rem = count & 15;
    int rbase = count & ~15;

    if (!big) {
        if (count >= 16) UCONV16(0, 0);
        if (count >= 32) UCONV16(16, 8);
        if (rem & 8) UCONV8(rbase, 16);
        if (rem & 4) UCONV4(rbase + (rem & 8), 20);
    } else {
        for (int j = beg; j < end; j += 4) {
            int4 s = *(const int4*)(srcadj + j);
            a0 = fmaf(wuCur[4 * j + k], cvt_lo(cmbI[s.x + lane]), a0);
            a1 = fmaf(wuCur[4 * j + 4 + k], cvt_lo(cmbI[s.y + lane]), a1);
            a2 = fmaf(wuCur[4 * j + 8 + k], cvt_lo(cmbI[s.z + lane]), a2);
            a3 = fmaf(wuCur[4 * j + 12 + k], cvt_lo(cmbI[s.w + lane]), a3);
        }
    }
    float acc = (a0 + a1) + (a2 + a3);

    if (flags & 1) {
        int i = node * DIM + lane;
        allemb[i] += acc;
        if (flags & 4) xnextU[i] = f2b(acc);
    }

    // routing score from register cache + fused per-slot S/weight update
    float ssu = red16(acc * acc);
    float u = acc / fmaxf(sqrtf(ssu), 1e-12f);
    bool b0 = lane & 1;
    bool b1 = lane & 2;
    bool b2 = lane & 4;
    bool b3 = lane & 8;

    if (!big) {
#define USC16(JOFF, TP0) do { \
        int j = beg + (JOFF); \
        float p0 = u * __uint_as_float(tp[(TP0) + 0] << 16); \
        float p1 = u * __uint_as_float(tp[(TP0) + 0] & 0xffff0000u); \
        float p2 = u * __uint_as_float(tp[(TP0) + 1] << 16); \
        float p3 = u * __uint_as_float(tp[(TP0) + 1] & 0xffff0000u); \
        float p4 = u * __uint_as_float(tp[(TP0) + 2] << 16); \
        float p5 = u * __uint_as_float(tp[(TP0) + 2] & 0xffff0000u); \
        float p6 = u * __uint_as_float(tp[(TP0) + 3] << 16); \
        float p7 = u * __uint_as_float(tp[(TP0) + 3] & 0xffff0000u); \
        float p8 = u * __uint_as_float(tp[(TP0) + 4] << 16); \
        float p9 = u * __uint_as_float(tp[(TP0) + 4] & 0xffff0000u); \
        float p10 = u * __uint_as_float(tp[(TP0) + 5] << 16); \
        float p11 = u * __uint_as_float(tp[(TP0) + 5] & 0xffff0000u); \
        float p12 = u * __uint_as_float(tp[(TP0) + 6] << 16); \
        float p13 = u * __uint_as_float(tp[(TP0) + 6] & 0xffff0000u); \
        float p14 = u * __uint_as_float(tp[(TP0) + 7] << 16); \
        float p15 = u * __uint_as_float(tp[(TP0) + 7] & 0xffff0000u); \
        float q0 = mixv(p0, p1, b0, 1); \
        float q1 = mixv(p2, p3, b0, 1); \
        float q2 = mixv(p4, p5, b0, 1); \
        float q3 = mixv(p6, p7, b0, 1); \
        float q4 = mixv(p8, p9, b0, 1); \
        float q5 = mixv(p10, p11, b0, 1); \
        float q6 = mixv(p12, p13, b0, 1); \
        float q7 = mixv(p14, p15, b0, 1); \
        float r0 = mixv(q0, q1, b1, 2); \
        float r1 = mixv(q2, q3, b1, 2); \
        float r2 = mixv(q4, q5, b1, 2); \
        float r3 = mixv(q6, q7, b1, 2); \
        float s0 = mixv(r0, r1, b2, 4); \
        float s1 = mixv(r2, r3, b2, 4); \
        float t0 = mixv(s0, s1, b3, 8); \
        fused_upd(j + (lane & 15), k, t0, true, \
                  wuCur, S4f, norm2, jit, wuN, wiN, last); \
} while (0)
        if (count >= 16) USC16(0, 0);
        if (count >= 32) USC16(16, 8);
        if (rem & 8) {
            int j = beg + rbase;
            float p0 = u * __uint_as_float(tp[16] << 16);
            float p1 = u * __uint_as_float(tp[16] & 0xffff0000u);
            float p2 = u * __uint_as_float(tp[17] << 16);
            float p3 = u * __uint_as_float(tp[17] & 0xffff0000u);
            float p4 = u * __uint_as_float(tp[18] << 16);
            float p5 = u * __uint_as_float(tp[18] & 0xffff0000u);
            float p6 = u * __uint_as_float(tp[19] << 16);
            float p7 = u * __uint_as_float(tp[19] & 0xffff0000u);
            float q0 = mixv(p0, p1, b0, 1);
            float q1 = mixv(p2, p3, b0, 1);
            float q2 = mixv(p4, p5, b0, 1);
            float q3 = mixv(p6, p7, b0, 1);
            float r0 = mixv(q0, q1, b1, 2);
            float r1 = mixv(q2, q3, b1, 2);
            float t0 = mixv(r0, r1, b2, 4);
            t0 += __shfl_xor(t0, 8);
            fused_upd(j + (lane & 7), k, t0, !(lane & 8),
                      wuCur, S4f, norm2, jit, wuN, wiN, last);
        }
        if (rem & 4) {
            int j = beg + rbase + (rem & 8);
            float p0 = u * __uint_as_float(tp[20] << 16);
            float p1 = u * __uint_as_float(tp[20] & 0xffff0000u);
            float p2 = u * __uint_as_float(tp[21] << 16);
            float p3 = u * __uint_as_float(tp[21] & 0xffff0000u);
            float q0 = mixv(p0, p1, b0, 1);
            float q1 = mixv(p2, p3, b0, 1);
            float r0 = mixv(q0, q1, b1, 2);
            r0 += __shfl_xor(r0, 4);
            r0 += __shfl_xor(r0, 8);
            fused_upd(j + (lane & 3), k, r0, !(lane & 12),
                      wuCur, S4f, norm2, jit, wuN, wiN, last);
        }
    } else {
        for (int j = beg; j < end; j += 4) {
            int4 s = *(const int4*)(srcadj + j);
            float p0 = red16(u * cvt_hi(cmbI[s.x + lane]));
            float p1 = red16(u * cvt_hi(cmbI[s.y + lane]));
            float p2 = red16(u * cvt_hi(cmbI[s.z + lane]));
            float p3 = red16(u * cvt_hi(cmbI[s.w + lane]));
            int sl = lane & 3;
            float dv = p0;
            dv = (sl == 1) ? p1 : dv;
            dv = (sl == 2) ? p2 : dv;
            dv = (sl == 3) ? p3 : dv;
            fused_upd(j + sl, k, dv, !(lane & 12),
                      wuCur, S4f, norm2, jit, wuN, wiN, last);
        }
    }
}

extern "C" void kernel_launch(void* const* d_in, const int* in_sizes, int n_in,
                              void* d_out, int out_size, void* d_ws, size_t ws_size,
                              hipStream_t stream) {
    const float* user = (const float*)d_in[0];
    const float* item = (const float*)d_in[1];
    const float* S_in = (const float*)d_in[2];
    const int* edge = (const int*)d_in[3];
    const int* row0 = edge;
    const int* col0 = edge + NE;

    float* out = (float*)d_out;
    float* allemb = out;              // NN*DIM floats
    float* Sfinal = out + NN * DIM;   // KF*NE floats

    char* ws = (char*)d_ws;
    size_t off = 0;
    auto carve = [&](size_t bytes) { void* p = ws + off; off += (bytes + 255) & ~(size_t)255; return p; };
    int* cnt = (int*)carve((NN + 1) * sizeof(int));
    int* cntp = (int*)carve((NN + 1) * sizeof(int));
    int* ptr = (int*)carve((NN + 1) * sizeof(int));
    int* pos = (int*)carve((NN + 1) * sizeof(int));
    int* bsum = (int*)carve(256 * sizeof(int));
    int* offs = (int*)carve(256 * sizeof(int));
    int* srcadj = (int*)carve((size_t)(NEPU_MAX + NEPI_MAX) * sizeof(int));
    int* jit = (int*)carve((size_t)NEPU_MAX * sizeof(int));
    int* jpos1 = (int*)carve((size_t)NE * sizeof(int));
    int* einv = (int*)carve((size_t)NEPU_MAX * sizeof(int));
    float* dinv = (float*)carve(NN * sizeof(float));
    float2* norm2 = (float2*)carve((size_t)NEPU_MAX * sizeof(float2));
    float4* Scur4 = (float4*)carve((size_t)NEPU_MAX * sizeof(float4));
    float4* wuA = (float4*)carve((size_t)NEPU_MAX * sizeof(float4));
    float4* wuB = (float4*)carve((size_t)NEPU_MAX * sizeof(float4));
    float4* wiA = (float4*)carve((size_t)NEPI_MAX * sizeof(float4));
    float4* wiB = (float4*)carve((size_t)NEPI_MAX * sizeof(float4));
    unsigned short* egoUA = (unsigned short*)carve((size_t)NUM_USER * DIM * 2);
    unsigned short* egoUB = (unsigned short*)carve((size_t)NUM_USER * DIM * 2);
    unsigned* cmbIA = (unsigned*)carve((size_t)NUM_ITEM * DIM * 4);
    unsigned* cmbIB = (unsigned*)carve((size_t)NUM_ITEM * DIM * 4);

    hipMemsetAsync(cnt, 0, (NN + 1) * sizeof(int), stream);

    k_count<<<(NE + 255) / 256, 256, 0, stream>>>(row0, col0, cnt);
    k_dinv_pad<<<(NN + 255) / 256, 256, 0, stream>>>(cnt, dinv, cntp);
    k_scan1<<<NBLK_SCAN, SCAN_CHUNK, 0, stream>>>(cntp, ptr, bsum);
    k_scan2<<<1, 256, 0, stream>>>(bsum, offs);
    k_scan3<<<(NN + 1 + 255) / 256, 256, 0, stream>>>(ptr, offs, pos);
    k_fill<<<(NE + 255) / 256, 256, 0, stream>>>(row0, col0, pos, ptr, srcadj,
                                                 jit, jpos1, einv);
    k_pad<<<(NN + 255) / 256, 256, 0, stream>>>(cnt, ptr, srcadj, einv, norm2,
                                                wuA, wuB, wiA, wiB);
    k_w0<<<(NEPU_MAX + 255) / 256, 256, 0, stream>>>(S_in, row0, col0, einv, jit,
                                                     dinv, ptr, norm2, wuA, wiA);
    k_init<<<(NN * 64 + 255) / 256, 256, 0, stream>>>(user, item, egoUA, cmbIA, allemb);

    unsigned short* egoU = egoUA;
    unsigned short* egoUn = egoUB;
    unsigned* cmbI = cmbIA;
    unsigned* cmbIn = cmbIB;
    float* wuCur = (float*)wuA;
    float* wuNxt = (float*)wuB;
    float* wiCur = (float*)wiA;
    float* wiNxt = (float*)wiB;
    for (int layer = 0; layer < 2; ++layer) {
        for (int it = 0; it < 2; ++it) {
            int flags = 0;
            if (it == 1) flags |= 1;                   // layer end: allemb += acc
            if (it == 1 && layer == 0) flags |= 4;     // write next ego (+item T)
            int last = (layer == 1 && it == 1) ? 1 : 0;
            // non-layer-end: item x_new is never consumed -> user-only grid
            int nlim = (it == 1) ? NN : NUM_USER;
            k_conv_score<<<(nlim * 64 + 255) / 256, 256, 0, stream>>>(
                ptr, srcadj, wuCur, wiCur, (float*)Scur4, norm2, jit,
                wuNxt, wiNxt, egoU, cmbI, egoUn, cmbIn, allemb, flags, last, nlim);
            float* t = wuCur; wuCur = wuNxt; wuNxt = t;
            t = wiCur; wiCur = wiNxt; wiNxt = t;
        }
        unsigned short* t = egoU; egoU = egoUn; egoUn = t;
        unsigned* tc = cmbI; cmbI = cmbIn; cmbIn = tc;
    }
    k_sout<<<(NE + 255) / 256, 256, 0, stream>>>(Scur4, jpos1, Sfinal);
}

// Round 6
// 424.471 us; speedup vs baseline: 1.3243x; 1.0387x over previous
//
#include <hip/hip_runtime.h>

#define NUM_USER 60000
#define NUM_ITEM 40000
#define NN 100000
#define NE 500000
#define DIM 64
#define KF 4
#define SCAN_CHUNK 512
#define NBLK_SCAN ((NN + 1 + SCAN_CHUNK - 1) / SCAN_CHUNK)
// padded slot-count upper bounds (each node rounds up to multiple of 4)
#define NEPU_MAX (NE + 3 * NUM_USER)   // 680000 user-side slots max
#define NEPI_MAX (NE + 3 * NUM_ITEM)   // 620000 item-side slots max
#define MAXU_SLOTS 44                  // register-cached user path handles <=44 slots
#define NB_INIT (NN * 64 / 256)        // 25000 blocks: one wave per node
#define NB_COUNT ((NE + 255) / 256)
#define NB_W0 ((NEPU_MAX + 255) / 256)
#define NB_PAD ((NN + 255) / 256)

// sum within each 16-lane group (butterfly: all lanes get result)
__device__ __forceinline__ float red16(float v) {
    v += __shfl_xor(v, 1);
    v += __shfl_xor(v, 2);
    v += __shfl_xor(v, 4);
    v += __shfl_xor(v, 8);
    return v;
}

__device__ __forceinline__ float b2f(unsigned short u) {
    return __uint_as_float(((unsigned)u) << 16);
}
__device__ __forceinline__ unsigned short f2b(float x) {
    unsigned u = __float_as_uint(x);
    u = (u + 0x7fffu + ((u >> 16) & 1u)) >> 16;   // RNE
    return (unsigned short)u;
}
// combined item word: high16 = T (bf16 bits), low16 = ego (bf16 bits)
__device__ __forceinline__ float cvt_lo(unsigned c) { return __uint_as_float(c << 16); }
__device__ __forceinline__ float cvt_hi(unsigned c) { return __uint_as_float(c & 0xffff0000u); }
// pack hi16 halves of two combined words: lo16(out)=hi16(c0), hi16(out)=hi16(c1)
__device__ __forceinline__ unsigned packhi(unsigned c0, unsigned c1) {
#if defined(__has_builtin) && __has_builtin(__builtin_amdgcn_perm)
    return __builtin_amdgcn_perm(c1, c0, 0x07060302u);
#else
    return (c0 >> 16) | (c1 & 0xffff0000u);
#endif
}
// mixed-butterfly level: lane keeps the value whose slot-bit matches its lane bit
__device__ __forceinline__ float mixv(float x, float y, bool b, int m) {
    return (b ? y : x) + __shfl_xor(b ? x : y, m);
}

__device__ __forceinline__ float4 softmax4(float4 s) {
    float m = fmaxf(fmaxf(s.x, s.y), fmaxf(s.z, s.w));
    float e0 = __expf(s.x - m), e1 = __expf(s.y - m);
    float e2 = __expf(s.z - m), e3 = __expf(s.w - m);
    float inv = 1.0f / (e0 + e1 + e2 + e3);
    return make_float4(e0 * inv, e1 * inv, e2 * inv, e3 * inv);
}

// Fused per-slot S/weight update. Lane holds dot for (slot jj, factor k);
// factor partners are lanes 16 apart. softmax(S_old) is reconstructed as
// w_cur * (1/n)  (w_cur is L1-hot from the conv loop) -- no S state traffic.
// snew = w*rn + dot; last: S4f <- snew (final output);
// else: w' = n * softmax_k(snew) -> wuN, wiN (dummy slots n=0: skipped).
__device__ __forceinline__ void fused_upd(int jj, int k, float dot, bool wr,
        const float* __restrict__ wuCur, float* __restrict__ S4f,
        const float2* __restrict__ norm2, const int* __restrict__ jit,
        float* __restrict__ wuN, float* __restrict__ wiN, int last) {
    float w = wuCur[4 * jj + k];
    float2 nn = norm2[jj];
    float snew = fmaf(w, nn.y, dot);
    if (last) {
        if (wr) S4f[4 * jj + k] = snew;
        return;
    }
    float m2 = fmaxf(snew, __shfl_xor(snew, 16));
    m2 = fmaxf(m2, __shfl_xor(m2, 32));
    float e2 = __expf(snew - m2);
    float s2 = e2 + __shfl_xor(e2, 16);
    s2 += __shfl_xor(s2, 32);
    if (wr && nn.x > 0.0f) {
        float wn = nn.x * e2 * (1.0f / s2);
        wuN[4 * jj + k] = wn;
        wiN[4 * jit[jj] + k] = wn;
    }
}

// merged: blocks [0, NB_INIT) = per-node init; rest = edge-parallel degree count.
// Users: egoU(bf16) + allemb. Items: cmbI = (tanh(l2n16)<<16)|ego.
__global__ void k_setup(const float* __restrict__ user, const float* __restrict__ item,
                        unsigned short* __restrict__ egoU, unsigned* __restrict__ cmbI,
                        float* __restrict__ allemb, const int* __restrict__ row0,
                        const int* __restrict__ col0, int* __restrict__ cnt) {
    int b = blockIdx.x;
    if (b < NB_INIT) {
        int node = (b * 256 + threadIdx.x) >> 6;   // < NN by construction
        int lane = threadIdx.x & 63;
        int i = node * DIM + lane;
        if (node < NUM_USER) {
            float v = user[i];
            egoU[i] = f2b(v);
            allemb[i] = v;
        } else {
            float v = item[i - NUM_USER * DIM];
            allemb[i] = v;
            float ss = red16(v * v);
            float t = tanhf(v / fmaxf(sqrtf(ss), 1e-12f));
            cmbI[i - NUM_USER * DIM] = (((unsigned)f2b(t)) << 16) | (unsigned)f2b(v);
        }
    } else {
        int e = (b - NB_INIT) * 256 + threadIdx.x;
        if (e >= NE) return;
        atomicAdd(&cnt[row0[e]], 1);
        atomicAdd(&cnt[col0[e]], 1);
    }
}

// --- 3-stage exclusive scan over padded counts -> ptr[NN+1]; dinv fused ---
__global__ void k_scan1(const int* __restrict__ cnt, float* __restrict__ dinv,
                        int* __restrict__ ptr, int* __restrict__ bsum) {
    __shared__ int sm[SCAN_CHUNK];
    int tid = threadIdx.x;
    int idx = blockIdx.x * SCAN_CHUNK + tid;
    int d = (idx < NN) ? cnt[idx] : 0;
    if (idx < NN) dinv[idx] = (d > 0) ? rsqrtf((float)d) : 0.0f;
    int x = (d + 3) & ~3;   // padded count; 0 stays 0
    sm[tid] = x;
    __syncthreads();
    for (int off = 1; off < SCAN_CHUNK; off <<= 1) {
        int v = (tid >= off) ? sm[tid - off] : 0;
        __syncthreads();
        sm[tid] += v;
        __syncthreads();
    }
    if (idx <= NN) ptr[idx] = sm[tid] - x;
    if (tid == SCAN_CHUNK - 1) bsum[blockIdx.x] = sm[tid];
}

__global__ void k_scan2(int* __restrict__ bsum, int* __restrict__ offs) {
    __shared__ int sm[256];
    int tid = threadIdx.x;
    int x = (tid < NBLK_SCAN) ? bsum[tid] : 0;
    sm[tid] = x;
    __syncthreads();
    for (int off = 1; off < 256; off <<= 1) {
        int v = (tid >= off) ? sm[tid - off] : 0;
        __syncthreads();
        sm[tid] += v;
        __syncthreads();
    }
    if (tid < NBLK_SCAN) offs[tid] = sm[tid] - x;
}

// finalize scan; also replicate into pos (removes the D2D memcpy dispatch)
__global__ void k_scan3(int* __restrict__ ptr, const int* __restrict__ offs,
                        int* __restrict__ pos) {
    int idx = blockIdx.x * blockDim.x + threadIdx.x;
    if (idx > NN) return;
    int v = ptr[idx] + offs[idx / SCAN_CHUNK];
    ptr[idx] = v;
    pos[idx] = v;
}

// fill CSR. user-side slots are [0, ptr[NUM_USER]); src stored ITEM-LOCAL,
// PRE-SCALED by DIM (<<6). jit[user_slot] = item-local slot of same edge;
// einv[user_slot] = edge id (dummies stay -1 from the 0xFF memset).
__global__ void k_fill(const int* __restrict__ row0, const int* __restrict__ col0,
                       int* __restrict__ pos, const int* __restrict__ ptr,
                       int* __restrict__ srcadj, int* __restrict__ jit,
                       int* __restrict__ jpos1, int* __restrict__ einv) {
    int e = blockIdx.x * blockDim.x + threadIdx.x;
    if (e >= NE) return;
    int r = row0[e], c = col0[e];
    int ptrU = ptr[NUM_USER];
    int j1 = atomicAdd(&pos[r], 1);   // user-side slot: dst=r, src=c (item-local)
    srcadj[j1] = (c - NUM_USER) << 6;
    jpos1[e] = j1;
    einv[j1] = e;
    int j0 = atomicAdd(&pos[c], 1);   // item-side slot: dst=c, src=r
    srcadj[j0] = r << 6;
    jit[j1] = j0 - ptrU;
}

// merged: blocks [0, NB_W0) = slot-parallel weight init (norm {n,1/n} + initial
// weights both orderings; dummies skipped, already zero from bulk memset);
// rest = dummy-slot srcadj=0 (zero weight makes the gathered value harmless).
__global__ void k_w0pad(const float* __restrict__ Sin, const int* __restrict__ row0,
                        const int* __restrict__ col0, const int* __restrict__ einv,
                        const int* __restrict__ jit, const float* __restrict__ dinv,
                        const int* __restrict__ ptr, const int* __restrict__ cnt,
                        int* __restrict__ srcadj, float2* __restrict__ norm2,
                        float4* __restrict__ wuA, float4* __restrict__ wiA) {
    int b = blockIdx.x;
    if (b < NB_W0) {
        int j = b * 256 + threadIdx.x;
        if (j >= ptr[NUM_USER]) return;
        int e = einv[j];
        if (e < 0) return;   // dummy: stays zero
        float n = dinv[row0[e]] * dinv[col0[e]];
        float4 s = make_float4(Sin[e], Sin[NE + e], Sin[2 * NE + e], Sin[3 * NE + e]);
        float4 p = softmax4(s);
        norm2[j] = make_float2(n, 1.0f / n);
        float4 w = make_float4(n * p.x, n * p.y, n * p.z, n * p.w);
        wuA[j] = w;
        wiA[jit[j]] = w;
    } else {
        int n = (b - NB_W0) * 256 + threadIdx.x;
        if (n >= NN) return;
        int realend = ptr[n] + cnt[n];
        int end = ptr[n + 1];
        for (int j = realend; j < end; ++j) srcadj[j] = 0;
    }
}

// Scur4 (slot order, written by last conv) -> Sout [4][E] original edge order
__global__ void k_sout(const float4* __restrict__ Scur4, const int* __restrict__ jpos1,
                       float* __restrict__ Sout) {
    int e = blockIdx.x * blockDim.x + threadIdx.x;
    if (e >= NE) return;
    float4 s = Scur4[jpos1[e]];
    Sout[e] = s.x;
    Sout[NE + e] = s.y;
    Sout[2 * NE + e] = s.z;
    Sout[3 * NE + e] = s.w;
}

// ---- user conv block macros: 16 outstanding gathers per issue point ----
// (srcadj values are pre-scaled by DIM)
#define UCONV16(JOFF, TP0) do { \
    int j = beg + (JOFF); \
    int4 sA = *(const int4*)(srcadj + j); \
    int4 sB = *(const int4*)(srcadj + j + 4); \
    int4 sC = *(const int4*)(srcadj + j + 8); \
    int4 sD = *(const int4*)(srcadj + j + 12); \
    unsigned c0 = cmbI[sA.x + lane]; \
    unsigned c1 = cmbI[sA.y + lane]; \
    unsigned c2 = cmbI[sA.z + lane]; \
    unsigned c3 = cmbI[sA.w + lane]; \
    unsigned c4 = cmbI[sB.x + lane]; \
    unsigned c5 = cmbI[sB.y + lane]; \
    unsigned c6 = cmbI[sB.z + lane]; \
    unsigned c7 = cmbI[sB.w + lane]; \
    unsigned c8 = cmbI[sC.x + lane]; \
    unsigned c9 = cmbI[sC.y + lane]; \
    unsigned c10 = cmbI[sC.z + lane]; \
    unsigned c11 = cmbI[sC.w + lane]; \
    unsigned c12 = cmbI[sD.x + lane]; \
    unsigned c13 = cmbI[sD.y + lane]; \
    unsigned c14 = cmbI[sD.z + lane]; \
    unsigned c15 = cmbI[sD.w + lane]; \
    a0 = fmaf(wuCur[4 * j + k], cvt_lo(c0), a0); \
    a1 = fmaf(wuCur[4 * j + 4 + k], cvt_lo(c1), a1); \
    a2 = fmaf(wuCur[4 * j + 8 + k], cvt_lo(c2), a2); \
    a3 = fmaf(wuCur[4 * j + 12 + k], cvt_lo(c3), a3); \
    a0 = fmaf(wuCur[4 * j + 16 + k], cvt_lo(c4), a0); \
    a1 = fmaf(wuCur[4 * j + 20 + k], cvt_lo(c5), a1); \
    a2 = fmaf(wuCur[4 * j + 24 + k], cvt_lo(c6), a2); \
    a3 = fmaf(wuCur[4 * j + 28 + k], cvt_lo(c7), a3); \
    a0 = fmaf(wuCur[4 * j + 32 + k], cvt_lo(c8), a0); \
    a1 = fmaf(wuCur[4 * j + 36 + k], cvt_lo(c9), a1); \
    a2 = fmaf(wuCur[4 * j + 40 + k], cvt_lo(c10), a2); \
    a3 = fmaf(wuCur[4 * j + 44 + k], cvt_lo(c11), a3); \
    a0 = fmaf(wuCur[4 * j + 48 + k], cvt_lo(c12), a0); \
    a1 = fmaf(wuCur[4 * j + 52 + k], cvt_lo(c13), a1); \
    a2 = fmaf(wuCur[4 * j + 56 + k], cvt_lo(c14), a2); \
    a3 = fmaf(wuCur[4 * j + 60 + k], cvt_lo(c15), a3); \
    tp[(TP0) + 0] = packhi(c0, c1); \
    tp[(TP0) + 1] = packhi(c2, c3); \
    tp[(TP0) + 2] = packhi(c4, c5); \
    tp[(TP0) + 3] = packhi(c6, c7); \
    tp[(TP0) + 4] = packhi(c8, c9); \
    tp[(TP0) + 5] = packhi(c10, c11); \
    tp[(TP0) + 6] = packhi(c12, c13); \
    tp[(TP0) + 7] = packhi(c14, c15); \
} while (0)

#define UCONV8(JOFF, TP0) do { \
    int j = beg + (JOFF); \
    int4 sA = *(const int4*)(srcadj + j); \
    int4 sB = *(const int4*)(srcadj + j + 4); \
    unsigned c0 = cmbI[sA.x + lane]; \
    unsigned c1 = cmbI[sA.y + lane]; \
    unsigned c2 = cmbI[sA.z + lane]; \
    unsigned c3 = cmbI[sA.w + lane]; \
    unsigned c4 = cmbI[sB.x + lane]; \
    unsigned c5 = cmbI[sB.y + lane]; \
    unsigned c6 = cmbI[sB.z + lane]; \
    unsigned c7 = cmbI[sB.w + lane]; \
    a0 = fmaf(wuCur[4 * j + k], cvt_lo(c0), a0); \
    a1 = fmaf(wuCur[4 * j + 4 + k], cvt_lo(c1), a1); \
    a2 = fmaf(wuCur[4 * j + 8 + k], cvt_lo(c2), a2); \
    a3 = fmaf(wuCur[4 * j + 12 + k], cvt_lo(c3), a3); \
    a0 = fmaf(wuCur[4 * j + 16 + k], cvt_lo(c4), a0); \
    a1 = fmaf(wuCur[4 * j + 20 + k], cvt_lo(c5), a1); \
    a2 = fmaf(wuCur[4 * j + 24 + k], cvt_lo(c6), a2); \
    a3 = fmaf(wuCur[4 * j + 28 + k], cvt_lo(c7), a3); \
    tp[(TP0) + 0] = packhi(c0, c1); \
    tp[(TP0) + 1] = packhi(c2, c3); \
    tp[(TP0) + 2] = packhi(c4, c5); \
    tp[(TP0) + 3] = packhi(c6, c7); \
} while (0)

#define UCONV4(JOFF, TP0) do { \
    int j = beg + (JOFF); \
    int4 sA = *(const int4*)(srcadj + j); \
    unsigned c0 = cmbI[sA.x + lane]; \
    unsigned c1 = cmbI[sA.y + lane]; \
    unsigned c2 = cmbI[sA.z + lane]; \
    unsigned c3 = cmbI[sA.w + lane]; \
    a0 = fmaf(wuCur[4 * j + k], cvt_lo(c0), a0); \
    a1 = fmaf(wuCur[4 * j + 4 + k], cvt_lo(c1), a1); \
    a2 = fmaf(wuCur[4 * j + 8 + k], cvt_lo(c2), a2); \
    a3 = fmaf(wuCur[4 * j + 12 + k], cvt_lo(c3), a3); \
    tp[(TP0) + 0] = packhi(c0, c1); \
    tp[(TP0) + 1] = packhi(c2, c3); \
} while (0)

// fused gather conv + routing score + S/weight update.
// wave per node; lane = dim, k = lane>>4 = factor.
// nlim: NUM_USER on non-layer-end dispatches (item conv output unused there),
// NN on layer-end dispatches.
// __launch_bounds__(256,4): allow ~128 VGPR so the 16-deep gather blocks keep
// 16 loads in flight (round-5 VGPR=36 showed the compiler serializing them).
// flags: 1 = layer end (allemb += acc), 4 = write next ego (items: +tanh T)
__global__ __launch_bounds__(256, 4) void k_conv_score(
        const int* __restrict__ ptr, const int* __restrict__ srcadj,
        const float* __restrict__ wuCur, const float* __restrict__ wiCur,
        float* __restrict__ S4f, const float2* __restrict__ norm2,
        const int* __restrict__ jit, float* __restrict__ wuN,
        float* __restrict__ wiN, const unsigned short* __restrict__ egoU,
        const unsigned* __restrict__ cmbI, unsigned short* __restrict__ xnextU,
        unsigned* __restrict__ cmbNext, float* __restrict__ allemb,
        int flags, int last, int nlim) {
    int node = (blockIdx.x * blockDim.x + threadIdx.x) >> 6;
    int lane = threadIdx.x & 63;
    if (node >= nlim) return;
    int beg = __builtin_amdgcn_readfirstlane(ptr[node]);
    int end = __builtin_amdgcn_readfirstlane(ptr[node + 1]);
    int count = end - beg;
    int k = lane >> 4;

    float a0 = 0.0f, a1 = 0.0f, a2 = 0.0f, a3 = 0.0f;

    if (node >= NUM_USER) {
        // ---- item side: conv only, 16-deep (runs only on layer-end) ----
        int ptrU = __builtin_amdgcn_readfirstlane(ptr[NUM_USER]);
        const float* wT = wiCur + (size_t)4 * (beg - ptrU);
        int t = 0;
        for (; t + 16 <= count; t += 16) {
            int4 sA = *(const int4*)(srcadj + beg + t);
            int4 sB = *(const int4*)(srcadj + beg + t + 4);
            int4 sC = *(const int4*)(srcadj + beg + t + 8);
            int4 sD = *(const int4*)(srcadj + beg + t + 12);
            a0 = fmaf(wT[4 * t + k], b2f(egoU[sA.x + lane]), a0);
            a1 = fmaf(wT[4 * t + 4 + k], b2f(egoU[sA.y + lane]), a1);
            a2 = fmaf(wT[4 * t + 8 + k], b2f(egoU[sA.z + lane]), a2);
            a3 = fmaf(wT[4 * t + 12 + k], b2f(egoU[sA.w + lane]), a3);
            a0 = fmaf(wT[4 * t + 16 + k], b2f(egoU[sB.x + lane]), a0);
            a1 = fmaf(wT[4 * t + 20 + k], b2f(egoU[sB.y + lane]), a1);
            a2 = fmaf(wT[4 * t + 24 + k], b2f(egoU[sB.z + lane]), a2);
            a3 = fmaf(wT[4 * t + 28 + k], b2f(egoU[sB.w + lane]), a3);
            a0 = fmaf(wT[4 * t + 32 + k], b2f(egoU[sC.x + lane]), a0);
            a1 = fmaf(wT[4 * t + 36 + k], b2f(egoU[sC.y + lane]), a1);
            a2 = fmaf(wT[4 * t + 40 + k], b2f(egoU[sC.z + lane]), a2);
            a3 = fmaf(wT[4 * t + 44 + k], b2f(egoU[sC.w + lane]), a3);
            a0 = fmaf(wT[4 * t + 48 + k], b2f(egoU[sD.x + lane]), a0);
            a1 = fmaf(wT[4 * t + 52 + k], b2f(egoU[sD.y + lane]), a1);
            a2 = fmaf(wT[4 * t + 56 + k], b2f(egoU[sD.z + lane]), a2);
            a3 = fmaf(wT[4 * t + 60 + k], b2f(egoU[sD.w + lane]), a3);
        }
        if (count & 8) {
            int4 sA = *(const int4*)(srcadj + beg + t);
            int4 sB = *(const int4*)(srcadj + beg + t + 4);
            a0 = fmaf(wT[4 * t + k], b2f(egoU[sA.x + lane]), a0);
            a1 = fmaf(wT[4 * t + 4 + k], b2f(egoU[sA.y + lane]), a1);
            a2 = fmaf(wT[4 * t + 8 + k], b2f(egoU[sA.z + lane]), a2);
            a3 = fmaf(wT[4 * t + 12 + k], b2f(egoU[sA.w + lane]), a3);
            a0 = fmaf(wT[4 * t + 16 + k], b2f(egoU[sB.x + lane]), a0);
            a1 = fmaf(wT[4 * t + 20 + k], b2f(egoU[sB.y + lane]), a1);
            a2 = fmaf(wT[4 * t + 24 + k], b2f(egoU[sB.z + lane]), a2);
            a3 = fmaf(wT[4 * t + 28 + k], b2f(egoU[sB.w + lane]), a3);
            t += 8;
        }
        if (count & 4) {
            int4 sA = *(const int4*)(srcadj + beg + t);
            a0 = fmaf(wT[4 * t + k], b2f(egoU[sA.x + lane]), a0);
            a1 = fmaf(wT[4 * t + 4 + k], b2f(egoU[sA.y + lane]), a1);
            a2 = fmaf(wT[4 * t + 8 + k], b2f(egoU[sA.z + lane]), a2);
            a3 = fmaf(wT[4 * t + 12 + k], b2f(egoU[sA.w + lane]), a3);
        }
        float acc = (a0 + a1) + (a2 + a3);
        if (flags & 1) {
            int i = node * DIM + lane;
            allemb[i] += acc;
            if (flags & 4) {
                float ss = red16(acc * acc);
                float tt = tanhf(acc / fmaxf(sqrtf(ss), 1e-12f));
                cmbNext[i - NUM_USER * DIM] =
                    (((unsigned)f2b(tt)) << 16) | (unsigned)f2b(acc);
            }
        }
        return;
    }

    // ---- user side: conv + routing score + fused S/w update ----
    unsigned tp[22];          // packed T cache: 2 slots/word, static-indexed
    bool big = count > MAXU_SLOTS;   // wave-uniform fallback (statistically never)
    int rem = count & 15;
    int rbase = count & ~15;

    if (!big) {
        if (count >= 16) UCONV16(0, 0);
        if (count >= 32) UCONV16(16, 8);
        if (rem & 8) UCONV8(rbase, 16);
        if (rem & 4) UCONV4(rbase + (rem & 8), 20);
    } else {
        for (int j = beg; j < end; j += 4) {
            int4 s = *(const int4*)(srcadj + j);
            a0 = fmaf(wuCur[4 * j + k], cvt_lo(cmbI[s.x + lane]), a0);
            a1 = fmaf(wuCur[4 * j + 4 + k], cvt_lo(cmbI[s.y + lane]), a1);
            a2 = fmaf(wuCur[4 * j + 8 + k], cvt_lo(cmbI[s.z + lane]), a2);
            a3 = fmaf(wuCur[4 * j + 12 + k], cvt_lo(cmbI[s.w + lane]), a3);
        }
    }
    float acc = (a0 + a1) + (a2 + a3);

    if (flags & 1) {
        int i = node * DIM + lane;
        allemb[i] += acc;
        if (flags & 4) xnextU[i] = f2b(acc);
    }

    // routing score from register cache + fused per-slot S/weight update
    float ssu = red16(acc * acc);
    float u = acc / fmaxf(sqrtf(ssu), 1e-12f);
    bool b0 = lane & 1;
    bool b1 = lane & 2;
    bool b2 = lane & 4;
    bool b3 = lane & 8;

    if (!big) {
#define USC16(JOFF, TP0) do { \
        int j = beg + (JOFF); \
        float p0 = u * __uint_as_float(tp[(TP0) + 0] << 16); \
        float p1 = u * __uint_as_float(tp[(TP0) + 0] & 0xffff0000u); \
        float p2 = u * __uint_as_float(tp[(TP0) + 1] << 16); \
        float p3 = u * __uint_as_float(tp[(TP0) + 1] & 0xffff0000u); \
        float p4 = u * __uint_as_float(tp[(TP0) + 2] << 16); \
        float p5 = u * __uint_as_float(tp[(TP0) + 2] & 0xffff0000u); \
        float p6 = u * __uint_as_float(tp[(TP0) + 3] << 16); \
        float p7 = u * __uint_as_float(tp[(TP0) + 3] & 0xffff0000u); \
        float p8 = u * __uint_as_float(tp[(TP0) + 4] << 16); \
        float p9 = u * __uint_as_float(tp[(TP0) + 4] & 0xffff0000u); \
        float p10 = u * __uint_as_float(tp[(TP0) + 5] << 16); \
        float p11 = u * __uint_as_float(tp[(TP0) + 5] & 0xffff0000u); \
        float p12 = u * __uint_as_float(tp[(TP0) + 6] << 16); \
        float p13 = u * __uint_as_float(tp[(TP0) + 6] & 0xffff0000u); \
        float p14 = u * __uint_as_float(tp[(TP0) + 7] << 16); \
        float p15 = u * __uint_as_float(tp[(TP0) + 7] & 0xffff0000u); \
        float q0 = mixv(p0, p1, b0, 1); \
        float q1 = mixv(p2, p3, b0, 1); \
        float q2 = mixv(p4, p5, b0, 1); \
        float q3 = mixv(p6, p7, b0, 1); \
        float q4 = mixv(p8, p9, b0, 1); \
        float q5 = mixv(p10, p11, b0, 1); \
        float q6 = mixv(p12, p13, b0, 1); \
        float q7 = mixv(p14, p15, b0, 1); \
        float r0 = mixv(q0, q1, b1, 2); \
        float r1 = mixv(q2, q3, b1, 2); \
        float r2 = mixv(q4, q5, b1, 2); \
        float r3 = mixv(q6, q7, b1, 2); \
        float s0 = mixv(r0, r1, b2, 4); \
        float s1 = mixv(r2, r3, b2, 4); \
        float t0 = mixv(s0, s1, b3, 8); \
        fused_upd(j + (lane & 15), k, t0, true, \
                  wuCur, S4f, norm2, jit, wuN, wiN, last); \
} while (0)
        if (count >= 16) USC16(0, 0);
        if (count >= 32) USC16(16, 8);
        if (rem & 8) {
            int j = beg + rbase;
            float p0 = u * __uint_as_float(tp[16] << 16);
            float p1 = u * __uint_as_float(tp[16] & 0xffff0000u);
            float p2 = u * __uint_as_float(tp[17] << 16);
            float p3 = u * __uint_as_float(tp[17] & 0xffff0000u);
            float p4 = u * __uint_as_float(tp[18] << 16);
            float p5 = u * __uint_as_float(tp[18] & 0xffff0000u);
            float p6 = u * __uint_as_float(tp[19] << 16);
            float p7 = u * __uint_as_float(tp[19] & 0xffff0000u);
            float q0 = mixv(p0, p1, b0, 1);
            float q1 = mixv(p2, p3, b0, 1);
            float q2 = mixv(p4, p5, b0, 1);
            float q3 = mixv(p6, p7, b0, 1);
            float r0 = mixv(q0, q1, b1, 2);
            float r1 = mixv(q2, q3, b1, 2);
            float t0 = mixv(r0, r1, b2, 4);
            t0 += __shfl_xor(t0, 8);
            fused_upd(j + (lane & 7), k, t0, !(lane & 8),
                      wuCur, S4f, norm2, jit, wuN, wiN, last);
        }
        if (rem & 4) {
            int j = beg + rbase + (rem & 8);
            float p0 = u * __uint_as_float(tp[20] << 16);
            float p1 = u * __uint_as_float(tp[20] & 0xffff0000u);
            float p2 = u * __uint_as_float(tp[21] << 16);
            float p3 = u * __uint_as_float(tp[21] & 0xffff0000u);
            float q0 = mixv(p0, p1, b0, 1);
            float q1 = mixv(p2, p3, b0, 1);
            float r0 = mixv(q0, q1, b1, 2);
            r0 += __shfl_xor(r0, 4);
            r0 += __shfl_xor(r0, 8);
            fused_upd(j + (lane & 3), k, r0, !(lane & 12),
                      wuCur, S4f, norm2, jit, wuN, wiN, last);
        }
    } else {
        for (int j = beg; j < end; j += 4) {
            int4 s = *(const int4*)(srcadj + j);
            float p0 = red16(u * cvt_hi(cmbI[s.x + lane]));
            float p1 = red16(u * cvt_hi(cmbI[s.y + lane]));
            float p2 = red16(u * cvt_hi(cmbI[s.z + lane]));
            float p3 = red16(u * cvt_hi(cmbI[s.w + lane]));
            int sl = lane & 3;
            float dv = p0;
            dv = (sl == 1) ? p1 : dv;
            dv = (sl == 2) ? p2 : dv;
            dv = (sl == 3) ? p3 : dv;
            fused_upd(j + sl, k, dv, !(lane & 12),
                      wuCur, S4f, norm2, jit, wuN, wiN, last);
        }
    }
}

extern "C" void kernel_launch(void* const* d_in, const int* in_sizes, int n_in,
                              void* d_out, int out_size, void* d_ws, size_t ws_size,
                              hipStream_t stream) {
    const float* user = (const float*)d_in[0];
    const float* item = (const float*)d_in[1];
    const float* S_in = (const float*)d_in[2];
    const int* edge = (const int*)d_in[3];
    const int* row0 = edge;
    const int* col0 = edge + NE;

    float* out = (float*)d_out;
    float* allemb = out;              // NN*DIM floats
    float* Sfinal = out + NN * DIM;   // KF*NE floats

    char* ws = (char*)d_ws;
    size_t off = 0;
    auto carve = [&](size_t bytes) { void* p = ws + off; off += (bytes + 255) & ~(size_t)255; return p; };
    int* cnt = (int*)carve((NN + 1) * sizeof(int));
    int* ptr = (int*)carve((NN + 1) * sizeof(int));
    int* pos = (int*)carve((NN + 1) * sizeof(int));
    int* bsum = (int*)carve(256 * sizeof(int));
    int* offs = (int*)carve(256 * sizeof(int));
    int* srcadj = (int*)carve((size_t)(NEPU_MAX + NEPI_MAX) * sizeof(int));
    int* jit = (int*)carve((size_t)NEPU_MAX * sizeof(int));
    int* jpos1 = (int*)carve((size_t)NE * sizeof(int));
    int* einv = (int*)carve((size_t)NEPU_MAX * sizeof(int));
    float* dinv = (float*)carve(NN * sizeof(float));
    float4* Scur4 = (float4*)carve((size_t)NEPU_MAX * sizeof(float4));
    // contiguous zero-region: norm2 | wuA | wuB | wiA | wiB  (one bulk memset)
    size_t zbeg = off;
    float2* norm2 = (float2*)carve((size_t)NEPU_MAX * sizeof(float2));
    float4* wuA = (float4*)carve((size_t)NEPU_MAX * sizeof(float4));
    float4* wuB = (float4*)carve((size_t)NEPU_MAX * sizeof(float4));
    float4* wiA = (float4*)carve((size_t)NEPI_MAX * sizeof(float4));
    float4* wiB = (float4*)carve((size_t)NEPI_MAX * sizeof(float4));
    size_t zlen = off - zbeg;
    unsigned short* egoUA = (unsigned short*)carve((size_t)NUM_USER * DIM * 2);
    unsigned short* egoUB = (unsigned short*)carve((size_t)NUM_USER * DIM * 2);
    unsigned* cmbIA = (unsigned*)carve((size_t)NUM_ITEM * DIM * 4);
    unsigned* cmbIB = (unsigned*)carve((size_t)NUM_ITEM * DIM * 4);

    hipMemsetAsync(cnt, 0, (NN + 1) * sizeof(int), stream);
    hipMemsetAsync(einv, 0xFF, (size_t)NEPU_MAX * sizeof(int), stream);  // all -1
    hipMemsetAsync(ws + zbeg, 0, zlen, stream);

    k_setup<<<NB_INIT + NB_COUNT, 256, 0, stream>>>(user, item, egoUA, cmbIA,
                                                    allemb, row0, col0, cnt);
    k_scan1<<<NBLK_SCAN, SCAN_CHUNK, 0, stream>>>(cnt, dinv, ptr, bsum);
    k_scan2<<<1, 256, 0, stream>>>(bsum, offs);
    k_scan3<<<(NN + 1 + 255) / 256, 256, 0, stream>>>(ptr, offs, pos);
    k_fill<<<(NE + 255) / 256, 256, 0, stream>>>(row0, col0, pos, ptr, srcadj,
                                                 jit, jpos1, einv);
    k_w0pad<<<NB_W0 + NB_PAD, 256, 0, stream>>>(S_in, row0, col0, einv, jit,
                                                dinv, ptr, cnt, srcadj,
                                                norm2, wuA, wiA);

    unsigned short* egoU = egoUA;
    unsigned short* egoUn = egoUB;
    unsigned* cmbI = cmbIA;
    unsigned* cmbIn = cmbIB;
    float* wuCur = (float*)wuA;
    float* wuNxt = (float*)wuB;
    float* wiCur = (float*)wiA;
    float* wiNxt = (float*)wiB;
    for (int layer = 0; layer < 2; ++layer) {
        for (int it = 0; it < 2; ++it) {
            int flags = 0;
            if (it == 1) flags |= 1;                   // layer end: allemb += acc
            if (it == 1 && layer == 0) flags |= 4;     // write next ego (+item T)
            int last = (layer == 1 && it == 1) ? 1 : 0;
            // non-layer-end: item x_new is never consumed -> user-only grid
            int nlim = (it == 1) ? NN : NUM_USER;
            k_conv_score<<<(nlim * 64 + 255) / 256, 256, 0, stream>>>(
                ptr, srcadj, wuCur, wiCur, (float*)Scur4, norm2, jit,
                wuNxt, wiNxt, egoU, cmbI, egoUn, cmbIn, allemb, flags, last, nlim);
            float* t = wuCur; wuCur = wuNxt; wuNxt = t;
            t = wiCur; wiCur = wiNxt; wiNxt = t;
        }
        unsigned short* t = egoU; egoU = egoUn; egoUn = t;
        unsigned* tc = cmbI; cmbI = cmbIn; cmbIn = tc;
    }
    k_sout<<<(NE + 255) / 256, 256, 0, stream>>>(Scur4, jpos1, Sfinal);
}